// Round 1
// baseline (4310.859 us; speedup 1.0000x reference)
//
#include <hip/hip_runtime.h>
#include <math.h>

#define B_SZ 2
#define L_SZ 2048
#define DMODEL 1024
#define DINNER 2048
#define DSTATE 16
#define DCONV 4
#define DTRANK 64

__device__ __forceinline__ float silu_f(float x) {
    return x / (1.0f + expf(-x));
}

__device__ __forceinline__ float softplus_f(float x) {
    return (x > 20.0f) ? x : log1pf(expf(x));
}

// Generic fp32 tiled GEMM: C[M,N] = A[M,K] @ B[K,N], row-major with strides.
// ACT==1: C = softplus(C + bias[col])
template <int ACT>
__global__ __launch_bounds__(256) void gemm_tiled(
    const float* __restrict__ A, const float* __restrict__ Bm,
    float* __restrict__ C, const float* __restrict__ bias,
    int M, int N, int K, int lda, int ldb, int ldc)
{
    __shared__ float As[16][65];   // [k][m], padded to dodge bank conflicts
    __shared__ float Bs[16][65];   // [k][n]

    const int tid  = threadIdx.x;
    const int row0 = blockIdx.y * 64;
    const int col0 = blockIdx.x * 64;
    const int ty = tid >> 4;   // 0..15 -> row group
    const int tx = tid & 15;   // 0..15 -> col group

    float acc[4][4] = {{0.f}};

    for (int k0 = 0; k0 < K; k0 += 16) {
        // Load A tile (64 rows x 16 k): consecutive tids read consecutive k (coalesced per row)
        #pragma unroll
        for (int i = 0; i < 4; i++) {
            int idx = tid + i * 256;
            int am = idx >> 4;
            int ak = idx & 15;
            int gr = row0 + am, gc = k0 + ak;
            float v = (gr < M && gc < K) ? A[gr * lda + gc] : 0.0f;
            As[ak][am] = v;
        }
        // Load B tile (16 k x 64 cols): consecutive tids read consecutive cols (coalesced)
        #pragma unroll
        for (int i = 0; i < 4; i++) {
            int idx = tid + i * 256;
            int bk = idx >> 6;
            int bn = idx & 63;
            int gr = k0 + bk, gc = col0 + bn;
            float v = (gr < K && gc < N) ? Bm[gr * ldb + gc] : 0.0f;
            Bs[bk][bn] = v;
        }
        __syncthreads();

        #pragma unroll
        for (int k = 0; k < 16; k++) {
            float a0 = As[k][ty * 4 + 0];
            float a1 = As[k][ty * 4 + 1];
            float a2 = As[k][ty * 4 + 2];
            float a3 = As[k][ty * 4 + 3];
            float b0 = Bs[k][tx * 4 + 0];
            float b1 = Bs[k][tx * 4 + 1];
            float b2 = Bs[k][tx * 4 + 2];
            float b3 = Bs[k][tx * 4 + 3];
            acc[0][0] += a0 * b0; acc[0][1] += a0 * b1; acc[0][2] += a0 * b2; acc[0][3] += a0 * b3;
            acc[1][0] += a1 * b0; acc[1][1] += a1 * b1; acc[1][2] += a1 * b2; acc[1][3] += a1 * b3;
            acc[2][0] += a2 * b0; acc[2][1] += a2 * b1; acc[2][2] += a2 * b2; acc[2][3] += a2 * b3;
            acc[3][0] += a3 * b0; acc[3][1] += a3 * b1; acc[3][2] += a3 * b2; acc[3][3] += a3 * b3;
        }
        __syncthreads();
    }

    #pragma unroll
    for (int i = 0; i < 4; i++) {
        int gr = row0 + ty * 4 + i;
        if (gr >= M) continue;
        #pragma unroll
        for (int j = 0; j < 4; j++) {
            int gc = col0 + tx * 4 + j;
            if (gc >= N) continue;
            float v = acc[i][j];
            if (ACT == 1) { v = softplus_f(v + bias[gc]); }
            C[gr * ldc + gc] = v;
        }
    }
}

// xc[b,l,d] = silu( sum_k xin[b,l-3+k,d]*conv_w[d,k] + conv_b[d] )
// xin is xz[:, 0:2048] with row stride 4096.
__global__ __launch_bounds__(256) void conv_silu_kernel(
    const float* __restrict__ xz, const float* __restrict__ conv_w,
    const float* __restrict__ conv_b, float* __restrict__ xc)
{
    int idx = blockIdx.x * 256 + threadIdx.x;          // over B*L*DINNER = 8388608
    if (idx >= B_SZ * L_SZ * DINNER) return;
    int d  = idx & (DINNER - 1);
    int bl = idx >> 11;                                 // DINNER = 2^11
    int l  = bl & (L_SZ - 1);
    float acc = conv_b[d];
    #pragma unroll
    for (int k = 0; k < DCONV; k++) {
        int ls = l - (DCONV - 1) + k;
        if (ls >= 0) acc += xz[(bl - (DCONV - 1) + k) * 4096 + d] * conv_w[d * DCONV + k];
    }
    xc[idx] = silu_f(acc);
}

// Sequential selective scan. One lane per (b,d) channel, h[16] in registers.
// grid = 16 blocks x 256 threads (2 batches x 8 d-blocks).
__global__ __launch_bounds__(256) void scan_kernel(
    const float* __restrict__ xc, const float* __restrict__ delta,
    const float* __restrict__ dbc, const float* __restrict__ A_log,
    const float* __restrict__ D_skip, float* __restrict__ y)
{
    __shared__ float BC[32];                            // [0:16)=Bm, [16:32)=Cm for current step
    const int tid = threadIdx.x;
    const int b   = blockIdx.x >> 3;
    const int d   = (blockIdx.x & 7) * 256 + tid;

    float A[DSTATE], h[DSTATE];
    #pragma unroll
    for (int s = 0; s < DSTATE; s++) {
        A[s] = -expf(A_log[d * DSTATE + s]);
        h[s] = 0.0f;
    }
    const float Dv = D_skip[d];
    const int base = b * L_SZ;

    for (int l = 0; l < L_SZ; l++) {
        const int t = base + l;
        __syncthreads();                                // prior iteration done with BC
        if (tid < 32) BC[tid] = dbc[t * 96 + DTRANK + tid];
        float dv = delta[t * DINNER + d];
        float uv = xc[t * DINNER + d];
        __syncthreads();

        float du = dv * uv;
        float yv = 0.0f;
        #pragma unroll
        for (int s = 0; s < DSTATE; s++) {
            float dA = expf(dv * A[s]);
            h[s] = dA * h[s] + du * BC[s];
            yv  += h[s] * BC[16 + s];
        }
        y[t * DINNER + d] = uv * Dv + yv;
    }
}

// y[i] *= silu(z[i]);  z = xz[:, 2048:4096]
__global__ __launch_bounds__(256) void gate_kernel(
    const float* __restrict__ xz, float* __restrict__ y)
{
    int idx = blockIdx.x * 256 + threadIdx.x;
    if (idx >= B_SZ * L_SZ * DINNER) return;
    int d  = idx & (DINNER - 1);
    int bl = idx >> 11;
    float z = xz[bl * 4096 + DINNER + d];
    y[idx] = y[idx] * silu_f(z);
}

extern "C" void kernel_launch(void* const* d_in, const int* in_sizes, int n_in,
                              void* d_out, int out_size, void* d_ws, size_t ws_size,
                              hipStream_t stream) {
    const float* x       = (const float*)d_in[0];
    const float* W_in    = (const float*)d_in[1];
    const float* conv_w  = (const float*)d_in[2];
    const float* conv_b  = (const float*)d_in[3];
    const float* W_xproj = (const float*)d_in[4];
    const float* W_dt    = (const float*)d_in[5];
    const float* b_dt    = (const float*)d_in[6];
    const float* A_log   = (const float*)d_in[7];
    const float* D_skip  = (const float*)d_in[8];
    const float* W_out   = (const float*)d_in[9];
    float* out = (float*)d_out;

    float* ws    = (float*)d_ws;
    float* xz    = ws;                       // 4096 x 4096        = 16777216
    float* xc    = xz    + 16777216;         // 4096 x 2048        =  8388608
    float* dbc   = xc    +  8388608;         // 4096 x 96          =   393216
    float* delta = dbc   +   393216;         // 4096 x 2048        =  8388608
    float* yb    = delta +  8388608;         // 4096 x 2048        =  8388608

    const int MT = 4096;  // B*L tokens

    // 1) xz = x @ W_in                        (4096 x 4096, K=1024)
    gemm_tiled<0><<<dim3(64, 64), 256, 0, stream>>>(
        x, W_in, xz, nullptr, MT, 4096, 1024, 1024, 4096, 4096);

    // 2) xc = silu(causal_dwconv(xin) + b)
    conv_silu_kernel<<<dim3(32768), 256, 0, stream>>>(xz, conv_w, conv_b, xc);

    // 3) dbc = xc @ W_xproj                   (4096 x 96, K=2048)
    gemm_tiled<0><<<dim3(2, 64), 256, 0, stream>>>(
        xc, W_xproj, dbc, nullptr, MT, 96, 2048, 2048, 96, 96);

    // 4) delta = softplus(dt_lo @ W_dt + b_dt) (4096 x 2048, K=64; dt_lo = dbc[:, :64])
    gemm_tiled<1><<<dim3(32, 64), 256, 0, stream>>>(
        dbc, W_dt, delta, b_dt, MT, 2048, 64, 96, 2048, 2048);

    // 5) y = selective_scan(...)
    scan_kernel<<<dim3(16), 256, 0, stream>>>(xc, delta, dbc, A_log, D_skip, yb);

    // 6) y *= silu(z)
    gate_kernel<<<dim3(32768), 256, 0, stream>>>(xz, yb);

    // 7) out = y @ W_out                      (4096 x 1024, K=2048)
    gemm_tiled<0><<<dim3(16, 64), 256, 0, stream>>>(
        yb, W_out, out, nullptr, MT, 1024, 2048, 2048, 1024, 1024);
}

// Round 2
// 1981.002 us; speedup vs baseline: 2.1761x; 2.1761x over previous
//
#include <hip/hip_runtime.h>
#include <math.h>

#define B_SZ 2
#define L_SZ 2048
#define DMODEL 1024
#define DINNER 2048
#define DSTATE 16
#define DCONV 4
#define DTRANK 64

#define CS 64                    // scan chunk size
#define NCH (L_SZ / CS)          // 32 chunks per batch

__device__ __forceinline__ float silu_f(float x) {
    return x / (1.0f + expf(-x));
}

__device__ __forceinline__ float softplus_f(float x) {
    return (x > 20.0f) ? x : log1pf(expf(x));
}

// Generic fp32 tiled GEMM: C[M,N] = A[M,K] @ B[K,N], row-major with strides.
// ACT==1: C = softplus(C + bias[col])
template <int ACT>
__global__ __launch_bounds__(256) void gemm_tiled(
    const float* __restrict__ A, const float* __restrict__ Bm,
    float* __restrict__ C, const float* __restrict__ bias,
    int M, int N, int K, int lda, int ldb, int ldc)
{
    __shared__ float As[16][65];
    __shared__ float Bs[16][65];

    const int tid  = threadIdx.x;
    const int row0 = blockIdx.y * 64;
    const int col0 = blockIdx.x * 64;
    const int ty = tid >> 4;
    const int tx = tid & 15;

    float acc[4][4] = {{0.f}};

    for (int k0 = 0; k0 < K; k0 += 16) {
        #pragma unroll
        for (int i = 0; i < 4; i++) {
            int idx = tid + i * 256;
            int am = idx >> 4;
            int ak = idx & 15;
            int gr = row0 + am, gc = k0 + ak;
            float v = (gr < M && gc < K) ? A[gr * lda + gc] : 0.0f;
            As[ak][am] = v;
        }
        #pragma unroll
        for (int i = 0; i < 4; i++) {
            int idx = tid + i * 256;
            int bk = idx >> 6;
            int bn = idx & 63;
            int gr = k0 + bk, gc = col0 + bn;
            float v = (gr < K && gc < N) ? Bm[gr * ldb + gc] : 0.0f;
            Bs[bk][bn] = v;
        }
        __syncthreads();

        #pragma unroll
        for (int k = 0; k < 16; k++) {
            float a0 = As[k][ty * 4 + 0];
            float a1 = As[k][ty * 4 + 1];
            float a2 = As[k][ty * 4 + 2];
            float a3 = As[k][ty * 4 + 3];
            float b0 = Bs[k][tx * 4 + 0];
            float b1 = Bs[k][tx * 4 + 1];
            float b2 = Bs[k][tx * 4 + 2];
            float b3 = Bs[k][tx * 4 + 3];
            acc[0][0] += a0 * b0; acc[0][1] += a0 * b1; acc[0][2] += a0 * b2; acc[0][3] += a0 * b3;
            acc[1][0] += a1 * b0; acc[1][1] += a1 * b1; acc[1][2] += a1 * b2; acc[1][3] += a1 * b3;
            acc[2][0] += a2 * b0; acc[2][1] += a2 * b1; acc[2][2] += a2 * b2; acc[2][3] += a2 * b3;
            acc[3][0] += a3 * b0; acc[3][1] += a3 * b1; acc[3][2] += a3 * b2; acc[3][3] += a3 * b3;
        }
        __syncthreads();
    }

    #pragma unroll
    for (int i = 0; i < 4; i++) {
        int gr = row0 + ty * 4 + i;
        if (gr >= M) continue;
        #pragma unroll
        for (int j = 0; j < 4; j++) {
            int gc = col0 + tx * 4 + j;
            if (gc >= N) continue;
            float v = acc[i][j];
            if (ACT == 1) { v = softplus_f(v + bias[gc]); }
            C[gr * ldc + gc] = v;
        }
    }
}

__global__ __launch_bounds__(256) void conv_silu_kernel(
    const float* __restrict__ xz, const float* __restrict__ conv_w,
    const float* __restrict__ conv_b, float* __restrict__ xc)
{
    int idx = blockIdx.x * 256 + threadIdx.x;
    if (idx >= B_SZ * L_SZ * DINNER) return;
    int d  = idx & (DINNER - 1);
    int bl = idx >> 11;
    int l  = bl & (L_SZ - 1);
    float acc = conv_b[d];
    #pragma unroll
    for (int k = 0; k < DCONV; k++) {
        int ls = l - (DCONV - 1) + k;
        if (ls >= 0) acc += xz[(bl - (DCONV - 1) + k) * 4096 + d] * conv_w[d * DCONV + k];
    }
    xc[idx] = silu_f(acc);
}

// ---- Chunked parallel selective scan ----------------------------------------
// h[l] = dA[l]*h[l-1] + dBu[l] is linear: over a chunk, h_out = P*h_in + E.
// pass1: per chunk compute P (decay product) and E (local end-state from 0).
// pass2: sequential combine over NCH chunks -> entry state Hin per chunk
//        (written in-place over E).
// pass3: re-run each chunk from Hin, emit y, fused with silu(z) gating.

// grid: B*NCH*(DINNER/256) = 2*32*8 = 512 blocks
__global__ __launch_bounds__(256) void scan_pass1(
    const float* __restrict__ xc, const float* __restrict__ delta,
    const float* __restrict__ dbc, const float* __restrict__ A_log,
    float* __restrict__ P, float* __restrict__ E)
{
    __shared__ float Bs[CS * DSTATE];          // B rows for the chunk
    const int tid = threadIdx.x;
    const int db  = blockIdx.x & 7;
    const int c   = (blockIdx.x >> 3) & (NCH - 1);
    const int b   = blockIdx.x >> 8;
    const int d   = db * 256 + tid;
    const int t0  = b * L_SZ + c * CS;

    // stage B for all CS steps (coalesced)
    for (int idx = tid; idx < CS * DSTATE; idx += 256) {
        int step = idx >> 4, i = idx & 15;
        Bs[idx] = dbc[(t0 + step) * 96 + DTRANK + i];
    }

    float A[DSTATE], Pr[DSTATE], Er[DSTATE];
    #pragma unroll
    for (int s = 0; s < DSTATE; s++) {
        A[s]  = -expf(A_log[d * DSTATE + s]);
        Pr[s] = 1.0f;
        Er[s] = 0.0f;
    }
    __syncthreads();

    for (int l = 0; l < CS; l++) {
        const int t = t0 + l;
        float dv = delta[t * DINNER + d];
        float uv = xc[t * DINNER + d];
        float du = dv * uv;
        #pragma unroll
        for (int s = 0; s < DSTATE; s++) {
            float dA = expf(dv * A[s]);
            Pr[s] *= dA;
            Er[s] = dA * Er[s] + du * Bs[l * DSTATE + s];
        }
    }

    const long long o = ((long long)((b * NCH + c) * DINNER) + d) * DSTATE;
    #pragma unroll
    for (int s = 0; s < DSTATE; s++) {
        P[o + s] = Pr[s];
        E[o + s] = Er[s];
    }
}

// grid: B*DINNER*DSTATE / 256 = 256 blocks. E is rewritten to Hin in place.
__global__ __launch_bounds__(256) void scan_pass2(
    const float* __restrict__ P, float* __restrict__ E)
{
    const int gid  = blockIdx.x * 256 + threadIdx.x;   // over 2*2048*16
    const int b    = gid >> 15;
    const int rest = gid & 32767;                      // d*16+s
    float h = 0.0f;
    for (int c = 0; c < NCH; c++) {
        const long long idx = (long long)(b * NCH + c) * (DINNER * DSTATE) + rest;
        float p = P[idx];
        float e = E[idx];
        E[idx] = h;                                    // entry state for chunk c
        h = p * h + e;
    }
}

// grid: 512 blocks. y may alias delta (each element read before written by its
// owning thread). Fuses the silu(z) gate.
__global__ __launch_bounds__(256) void scan_pass3(
    const float* __restrict__ xc, const float* __restrict__ delta,
    const float* __restrict__ dbc, const float* __restrict__ A_log,
    const float* __restrict__ D_skip, const float* __restrict__ Hin,
    const float* __restrict__ xz, float* __restrict__ y)
{
    __shared__ float BCs[CS * 2 * DSTATE];     // per step: [B(16) | C(16)]
    const int tid = threadIdx.x;
    const int db  = blockIdx.x & 7;
    const int c   = (blockIdx.x >> 3) & (NCH - 1);
    const int b   = blockIdx.x >> 8;
    const int d   = db * 256 + tid;
    const int t0  = b * L_SZ + c * CS;

    for (int idx = tid; idx < CS * 2 * DSTATE; idx += 256) {
        int step = idx >> 5, i = idx & 31;
        BCs[idx] = dbc[(t0 + step) * 96 + DTRANK + i];
    }

    float A[DSTATE], h[DSTATE];
    const long long o = ((long long)((b * NCH + c) * DINNER) + d) * DSTATE;
    #pragma unroll
    for (int s = 0; s < DSTATE; s++) {
        A[s] = -expf(A_log[d * DSTATE + s]);
        h[s] = Hin[o + s];
    }
    const float Dv = D_skip[d];
    __syncthreads();

    for (int l = 0; l < CS; l++) {
        const int t = t0 + l;
        float dv = delta[t * DINNER + d];
        float uv = xc[t * DINNER + d];
        float du = dv * uv;
        float yv = 0.0f;
        #pragma unroll
        for (int s = 0; s < DSTATE; s++) {
            float dA = expf(dv * A[s]);
            h[s] = dA * h[s] + du * BCs[l * 32 + s];
            yv  += h[s] * BCs[l * 32 + DSTATE + s];
        }
        float z = xz[t * 4096 + DINNER + d];
        y[t * DINNER + d] = (uv * Dv + yv) * silu_f(z);
    }
}

extern "C" void kernel_launch(void* const* d_in, const int* in_sizes, int n_in,
                              void* d_out, int out_size, void* d_ws, size_t ws_size,
                              hipStream_t stream) {
    const float* x       = (const float*)d_in[0];
    const float* W_in    = (const float*)d_in[1];
    const float* conv_w  = (const float*)d_in[2];
    const float* conv_b  = (const float*)d_in[3];
    const float* W_xproj = (const float*)d_in[4];
    const float* W_dt    = (const float*)d_in[5];
    const float* b_dt    = (const float*)d_in[6];
    const float* A_log   = (const float*)d_in[7];
    const float* D_skip  = (const float*)d_in[8];
    const float* W_out   = (const float*)d_in[9];
    float* out = (float*)d_out;

    float* ws    = (float*)d_ws;
    float* xz    = ws;                       // 4096 x 4096  = 16777216 f
    float* xc    = xz    + 16777216;         // 4096 x 2048  =  8388608 f
    float* dbc   = xc    +  8388608;         // 4096 x 96    =   393216 f
    float* delta = dbc   +   393216;         // 4096 x 2048  =  8388608 f
    float* yb    = delta;                    // ALIAS: pass3 reads delta(t,d) before writing y(t,d)
    float* Pbuf  = delta + 8388608;          // 2*32*2048*16 =  2097152 f
    float* Ebuf  = Pbuf  + 2097152;          // 2*32*2048*16 =  2097152 f (becomes Hin)

    const int MT = 4096;  // B*L tokens

    // 1) xz = x @ W_in                        (4096 x 4096, K=1024)
    gemm_tiled<0><<<dim3(64, 64), 256, 0, stream>>>(
        x, W_in, xz, nullptr, MT, 4096, 1024, 1024, 4096, 4096);

    // 2) xc = silu(causal_dwconv(xin) + b)
    conv_silu_kernel<<<dim3(32768), 256, 0, stream>>>(xz, conv_w, conv_b, xc);

    // 3) dbc = xc @ W_xproj                   (4096 x 96, K=2048)
    gemm_tiled<0><<<dim3(2, 64), 256, 0, stream>>>(
        xc, W_xproj, dbc, nullptr, MT, 96, 2048, 2048, 96, 96);

    // 4) delta = softplus(dt_lo @ W_dt + b_dt) (4096 x 2048, K=64)
    gemm_tiled<1><<<dim3(32, 64), 256, 0, stream>>>(
        dbc, W_dt, delta, b_dt, MT, 2048, 64, 96, 2048, 2048);

    // 5) chunked selective scan + fused gate
    scan_pass1<<<dim3(512), 256, 0, stream>>>(xc, delta, dbc, A_log, Pbuf, Ebuf);
    scan_pass2<<<dim3(256), 256, 0, stream>>>(Pbuf, Ebuf);
    scan_pass3<<<dim3(512), 256, 0, stream>>>(xc, delta, dbc, A_log, D_skip,
                                              Ebuf, xz, yb);

    // 6) out = y @ W_out                      (4096 x 1024, K=2048)
    gemm_tiled<0><<<dim3(16, 64), 256, 0, stream>>>(
        yb, W_out, out, nullptr, MT, 1024, 2048, 2048, 1024, 1024);
}

// Round 3
// 604.433 us; speedup vs baseline: 7.1321x; 3.2775x over previous
//
#include <hip/hip_runtime.h>
#include <math.h>

#define B_SZ 2
#define L_SZ 2048
#define DMODEL 1024
#define DINNER 2048
#define DSTATE 16
#define DCONV 4
#define DTRANK 64

#define CS 64                    // scan chunk size
#define NCH (L_SZ / CS)          // 32 chunks per batch

typedef float f32x4 __attribute__((ext_vector_type(4)));
typedef __bf16 bf16x8 __attribute__((ext_vector_type(8)));

__device__ __forceinline__ float silu_f(float x) {
    return x / (1.0f + expf(-x));
}

__device__ __forceinline__ float softplus_f(float x) {
    return (x > 20.0f) ? x : log1pf(expf(x));
}

// fp32 -> bf16 round-to-nearest-even on raw bits
__device__ __forceinline__ unsigned short f2bf(float x) {
    unsigned int u = __float_as_uint(x);
    u = u + 0x7FFFu + ((u >> 16) & 1u);
    return (unsigned short)(u >> 16);
}

union Pack8 { unsigned short s[8]; uint4 v; };

// Transpose + cast: W[R,C] fp32 -> WT[C,R] bf16. Grid (C/32, R/32), 256 thr.
__global__ __launch_bounds__(256) void transpose_cast(
    const float* __restrict__ W, unsigned short* __restrict__ WT, int R, int C)
{
    __shared__ float t[32][33];
    const int tx = threadIdx.x & 31;
    const int ty = threadIdx.x >> 5;          // 0..7
    const int r0 = blockIdx.y * 32;
    const int c0 = blockIdx.x * 32;
    #pragma unroll
    for (int i = 0; i < 4; i++)
        t[ty + i * 8][tx] = W[(r0 + ty + i * 8) * C + c0 + tx];
    __syncthreads();
    #pragma unroll
    for (int i = 0; i < 4; i++)
        WT[(c0 + ty + i * 8) * R + r0 + tx] = f2bf(t[tx][ty + i * 8]);
}

// ---- bf16 MFMA GEMM, B pre-transposed -------------------------------------
// C[M,N](fp32) = A[M,K] @ BT[N,K]^T, fp32 accumulate.
// A_F32: A is fp32 (converted to bf16 during LDS staging) else bf16.
// ACT==1: C = softplus(C + bias[n]).
// Tile 128x128, BK=32. 256 threads = 4 waves in 2x2; each wave 64x64 via
// 4x4 mfma_f32_16x16x32_bf16. LDS stride 40 shorts (pad 8) -> conflict-free
// b128 fragment reads.
template <int ACT, int A_F32>
__global__ __launch_bounds__(256) void gemm_bt_mfma(
    const void* __restrict__ Aptr, const unsigned short* __restrict__ BT,
    float* __restrict__ C, const float* __restrict__ bias,
    int M, int N, int K, int lda, int ldb, int ldc)
{
    __shared__ unsigned short As[128 * 40];
    __shared__ unsigned short Bs[128 * 40];

    const int tid  = threadIdx.x;
    const int lane = tid & 63;
    const int wave = tid >> 6;
    const int wm   = wave >> 1;               // 0..1
    const int wn   = wave & 1;
    const int row0 = blockIdx.y * 128;
    const int col0 = blockIdx.x * 128;
    const int lq   = lane >> 4;               // quad 0..3
    const int lm   = lane & 15;

    f32x4 acc[4][4];
    #pragma unroll
    for (int i = 0; i < 4; i++)
        #pragma unroll
        for (int j = 0; j < 4; j++)
            #pragma unroll
            for (int r = 0; r < 4; r++) acc[i][j][r] = 0.0f;

    for (int k0 = 0; k0 < K; k0 += 32) {
        // stage A: 128 rows x 32 k
        #pragma unroll
        for (int it = 0; it < 2; it++) {
            int idx = (tid + it * 256) * 8;
            int r   = idx >> 5;               // 0..127
            int kk  = idx & 31;
            Pack8 p;
            if (A_F32) {
                const float* Af = (const float*)Aptr + (row0 + r) * lda + k0 + kk;
                float4 f0 = *(const float4*)Af;
                float4 f1 = *(const float4*)(Af + 4);
                p.s[0] = f2bf(f0.x); p.s[1] = f2bf(f0.y);
                p.s[2] = f2bf(f0.z); p.s[3] = f2bf(f0.w);
                p.s[4] = f2bf(f1.x); p.s[5] = f2bf(f1.y);
                p.s[6] = f2bf(f1.z); p.s[7] = f2bf(f1.w);
            } else {
                p.v = *(const uint4*)((const unsigned short*)Aptr +
                                      (row0 + r) * lda + k0 + kk);
            }
            *(uint4*)&As[r * 40 + kk] = p.v;
        }
        // stage BT: 128 n-rows x 32 k (guard n < N)
        #pragma unroll
        for (int it = 0; it < 2; it++) {
            int idx = (tid + it * 256) * 8;
            int r   = idx >> 5;
            int kk  = idx & 31;
            uint4 raw = {0u, 0u, 0u, 0u};
            if (col0 + r < N)
                raw = *(const uint4*)(BT + (col0 + r) * ldb + k0 + kk);
            *(uint4*)&Bs[r * 40 + kk] = raw;
        }
        __syncthreads();

        bf16x8 af[4], bf[4];
        #pragma unroll
        for (int i = 0; i < 4; i++)
            af[i] = *(const bf16x8*)&As[(wm * 64 + i * 16 + lm) * 40 + lq * 8];
        #pragma unroll
        for (int j = 0; j < 4; j++)
            bf[j] = *(const bf16x8*)&Bs[(wn * 64 + j * 16 + lm) * 40 + lq * 8];
        #pragma unroll
        for (int i = 0; i < 4; i++)
            #pragma unroll
            for (int j = 0; j < 4; j++)
                acc[i][j] = __builtin_amdgcn_mfma_f32_16x16x32_bf16(
                    af[i], bf[j], acc[i][j], 0, 0, 0);
        __syncthreads();
    }

    // epilogue: C/D layout col=lane&15, row=(lane>>4)*4+reg
    #pragma unroll
    for (int i = 0; i < 4; i++) {
        #pragma unroll
        for (int r = 0; r < 4; r++) {
            int row = row0 + wm * 64 + i * 16 + lq * 4 + r;
            #pragma unroll
            for (int j = 0; j < 4; j++) {
                int col = col0 + wn * 64 + j * 16 + lm;
                if (col < N) {
                    float v = acc[i][j][r];
                    if (ACT == 1) v = softplus_f(v + bias[col]);
                    C[row * ldc + col] = v;
                }
            }
        }
    }
}

__global__ __launch_bounds__(256) void conv_silu_kernel(
    const float* __restrict__ xz, const float* __restrict__ conv_w,
    const float* __restrict__ conv_b, float* __restrict__ xc)
{
    int idx = blockIdx.x * 256 + threadIdx.x;
    if (idx >= B_SZ * L_SZ * DINNER) return;
    int d  = idx & (DINNER - 1);
    int bl = idx >> 11;
    int l  = bl & (L_SZ - 1);
    float acc = conv_b[d];
    #pragma unroll
    for (int k = 0; k < DCONV; k++) {
        int ls = l - (DCONV - 1) + k;
        if (ls >= 0) acc += xz[(bl - (DCONV - 1) + k) * 4096 + d] * conv_w[d * DCONV + k];
    }
    xc[idx] = silu_f(acc);
}

// ---- Chunked parallel selective scan ----------------------------------------
__global__ __launch_bounds__(256) void scan_pass1(
    const float* __restrict__ xc, const float* __restrict__ delta,
    const float* __restrict__ dbc, const float* __restrict__ A_log,
    float* __restrict__ P, float* __restrict__ E)
{
    __shared__ float Bs[CS * DSTATE];
    const int tid = threadIdx.x;
    const int db  = blockIdx.x & 7;
    const int c   = (blockIdx.x >> 3) & (NCH - 1);
    const int b   = blockIdx.x >> 8;
    const int d   = db * 256 + tid;
    const int t0  = b * L_SZ + c * CS;

    for (int idx = tid; idx < CS * DSTATE; idx += 256) {
        int step = idx >> 4, i = idx & 15;
        Bs[idx] = dbc[(t0 + step) * 96 + DTRANK + i];
    }

    float A[DSTATE], Pr[DSTATE], Er[DSTATE];
    #pragma unroll
    for (int s = 0; s < DSTATE; s++) {
        A[s]  = -expf(A_log[d * DSTATE + s]);
        Pr[s] = 1.0f;
        Er[s] = 0.0f;
    }
    __syncthreads();

    for (int l = 0; l < CS; l++) {
        const int t = t0 + l;
        float dv = delta[t * DINNER + d];
        float uv = xc[t * DINNER + d];
        float du = dv * uv;
        #pragma unroll
        for (int s = 0; s < DSTATE; s++) {
            float dA = expf(dv * A[s]);
            Pr[s] *= dA;
            Er[s] = dA * Er[s] + du * Bs[l * DSTATE + s];
        }
    }

    const long long o = ((long long)((b * NCH + c) * DINNER) + d) * DSTATE;
    #pragma unroll
    for (int s = 0; s < DSTATE; s++) {
        P[o + s] = Pr[s];
        E[o + s] = Er[s];
    }
}

__global__ __launch_bounds__(256) void scan_pass2(
    const float* __restrict__ P, float* __restrict__ E)
{
    const int gid  = blockIdx.x * 256 + threadIdx.x;
    const int b    = gid >> 15;
    const int rest = gid & 32767;
    float h = 0.0f;
    for (int c = 0; c < NCH; c++) {
        const long long idx = (long long)(b * NCH + c) * (DINNER * DSTATE) + rest;
        float p = P[idx];
        float e = E[idx];
        E[idx] = h;
        h = p * h + e;
    }
}

// pass3: emit y in bf16 (A-operand of the out GEMM), fused silu(z) gate.
__global__ __launch_bounds__(256) void scan_pass3(
    const float* __restrict__ xc, const float* __restrict__ delta,
    const float* __restrict__ dbc, const float* __restrict__ A_log,
    const float* __restrict__ D_skip, const float* __restrict__ Hin,
    const float* __restrict__ xz, unsigned short* __restrict__ y16)
{
    __shared__ float BCs[CS * 2 * DSTATE];
    const int tid = threadIdx.x;
    const int db  = blockIdx.x & 7;
    const int c   = (blockIdx.x >> 3) & (NCH - 1);
    const int b   = blockIdx.x >> 8;
    const int d   = db * 256 + tid;
    const int t0  = b * L_SZ + c * CS;

    for (int idx = tid; idx < CS * 2 * DSTATE; idx += 256) {
        int step = idx >> 5, i = idx & 31;
        BCs[idx] = dbc[(t0 + step) * 96 + DTRANK + i];
    }

    float A[DSTATE], h[DSTATE];
    const long long o = ((long long)((b * NCH + c) * DINNER) + d) * DSTATE;
    #pragma unroll
    for (int s = 0; s < DSTATE; s++) {
        A[s] = -expf(A_log[d * DSTATE + s]);
        h[s] = Hin[o + s];
    }
    const float Dv = D_skip[d];
    __syncthreads();

    for (int l = 0; l < CS; l++) {
        const int t = t0 + l;
        float dv = delta[t * DINNER + d];
        float uv = xc[t * DINNER + d];
        float du = dv * uv;
        float yv = 0.0f;
        #pragma unroll
        for (int s = 0; s < DSTATE; s++) {
            float dA = expf(dv * A[s]);
            h[s] = dA * h[s] + du * BCs[l * 32 + s];
            yv  += h[s] * BCs[l * 32 + DSTATE + s];
        }
        float z = xz[t * 4096 + DINNER + d];
        y16[t * DINNER + d] = f2bf((uv * Dv + yv) * silu_f(z));
    }
}

extern "C" void kernel_launch(void* const* d_in, const int* in_sizes, int n_in,
                              void* d_out, int out_size, void* d_ws, size_t ws_size,
                              hipStream_t stream) {
    const float* x       = (const float*)d_in[0];
    const float* W_in    = (const float*)d_in[1];
    const float* conv_w  = (const float*)d_in[2];
    const float* conv_b  = (const float*)d_in[3];
    const float* W_xproj = (const float*)d_in[4];
    const float* W_dt    = (const float*)d_in[5];
    const float* b_dt    = (const float*)d_in[6];
    const float* A_log   = (const float*)d_in[7];
    const float* D_skip  = (const float*)d_in[8];
    const float* W_out   = (const float*)d_in[9];
    float* out = (float*)d_out;

    // workspace layout (floats) — 165.9 MB total
    float* ws      = (float*)d_ws;
    float* xz      = ws;                         // 16777216
    float* xc      = xz    + 16777216;           //  8388608
    float* dbc     = xc    +  8388608;           //   393216
    float* delta   = dbc   +   393216;           //  8388608
    float* Ebuf    = delta +  8388608;           //  2097152  (becomes Hin)
    float* regionF = Ebuf  +  2097152;           //  4194304 f multi-use:
    unsigned short* W_inT = (unsigned short*)regionF;        // 4194304 shorts
    float* Pbuf    = regionF + 2097152;                      // 2097152 f
    unsigned short* yb16  = (unsigned short*)regionF;        // aliases W_inT+P (both dead by pass3)
    unsigned short* W_xprojT = (unsigned short*)(regionF + 4194304); // 196608 shorts
    unsigned short* W_dtT    = W_xprojT + 196608;            // 131072 shorts
    unsigned short* W_outT   = W_dtT    + 131072;            // 2097152 shorts

    const int MT = 4096;  // B*L tokens

    // weight transposes + casts (bf16, B^T layout)
    transpose_cast<<<dim3(128, 32), 256, 0, stream>>>(W_in,    W_inT,    1024, 4096);
    transpose_cast<<<dim3(  3, 64), 256, 0, stream>>>(W_xproj, W_xprojT, 2048,   96);
    transpose_cast<<<dim3( 64,  2), 256, 0, stream>>>(W_dt,    W_dtT,      64, 2048);
    transpose_cast<<<dim3( 32, 64), 256, 0, stream>>>(W_out,   W_outT,   2048, 1024);

    // 1) xz = x @ W_in              (4096 x 4096, K=1024)
    gemm_bt_mfma<0, 1><<<dim3(32, 32), 256, 0, stream>>>(
        x, W_inT, xz, nullptr, MT, 4096, 1024, 1024, 1024, 4096);

    // 2) xc = silu(causal_dwconv(xin) + b)
    conv_silu_kernel<<<dim3(32768), 256, 0, stream>>>(xz, conv_w, conv_b, xc);

    // 3) dbc = xc @ W_xproj         (4096 x 96, K=2048)
    gemm_bt_mfma<0, 1><<<dim3(1, 32), 256, 0, stream>>>(
        xc, W_xprojT, dbc, nullptr, MT, 96, 2048, 2048, 2048, 96);

    // 4) delta = softplus(dt_lo @ W_dt + b_dt)  (4096 x 2048, K=64; A=dbc[:, :64] via lda=96)
    gemm_bt_mfma<1, 1><<<dim3(16, 32), 256, 0, stream>>>(
        dbc, W_dtT, delta, b_dt, MT, 2048, 64, 96, 64, 2048);

    // 5) chunked selective scan + fused gate (bf16 y out)
    scan_pass1<<<dim3(512), 256, 0, stream>>>(xc, delta, dbc, A_log, Pbuf, Ebuf);
    scan_pass2<<<dim3(256), 256, 0, stream>>>(Pbuf, Ebuf);
    scan_pass3<<<dim3(512), 256, 0, stream>>>(xc, delta, dbc, A_log, D_skip,
                                              Ebuf, xz, yb16);

    // 6) out = y @ W_out            (4096 x 1024, K=2048)
    gemm_bt_mfma<0, 0><<<dim3(8, 32), 256, 0, stream>>>(
        yb16, W_outT, out, nullptr, MT, 1024, 2048, 2048, 2048, 1024);
}

// Round 4
// 451.393 us; speedup vs baseline: 9.5501x; 1.3390x over previous
//
#include <hip/hip_runtime.h>
#include <math.h>

#define B_SZ 2
#define L_SZ 2048
#define DMODEL 1024
#define DINNER 2048
#define DSTATE 16
#define DCONV 4
#define DTRANK 64

#define CS 64                    // scan chunk size
#define NCH (L_SZ / CS)          // 32 chunks per batch

typedef float f32x4 __attribute__((ext_vector_type(4)));
typedef __bf16 bf16x8 __attribute__((ext_vector_type(8)));

__device__ __forceinline__ float silu_f(float x) {
    return x / (1.0f + __expf(-x));
}

__device__ __forceinline__ float softplus_f(float x) {
    return (x > 20.0f) ? x : log1pf(expf(x));   // keep precise: feeds exp in scan
}

// fp32 -> bf16 round-to-nearest-even on raw bits
__device__ __forceinline__ unsigned short f2bf(float x) {
    unsigned int u = __float_as_uint(x);
    u = u + 0x7FFFu + ((u >> 16) & 1u);
    return (unsigned short)(u >> 16);
}

union Pack8 { unsigned short s[8]; uint4 v; };

// Transpose + cast: W[R,C] fp32 -> WT[C,R] bf16. Grid (C/32, R/32), 256 thr.
__global__ __launch_bounds__(256) void transpose_cast(
    const float* __restrict__ W, unsigned short* __restrict__ WT, int R, int C)
{
    __shared__ float t[32][33];
    const int tx = threadIdx.x & 31;
    const int ty = threadIdx.x >> 5;          // 0..7
    const int r0 = blockIdx.y * 32;
    const int c0 = blockIdx.x * 32;
    #pragma unroll
    for (int i = 0; i < 4; i++)
        t[ty + i * 8][tx] = W[(r0 + ty + i * 8) * C + c0 + tx];
    __syncthreads();
    #pragma unroll
    for (int i = 0; i < 4; i++)
        WT[(c0 + ty + i * 8) * R + r0 + tx] = f2bf(t[tx][ty + i * 8]);
}

// ---- bf16 MFMA GEMM, B pre-transposed -------------------------------------
// C[M,N](fp32) = A[M,K] @ BT[N,K]^T, fp32 accumulate.
// Supports split-K via gridDim.z: block z covers k in [z*Kc, (z+1)*Kc) and
// writes to C + z*M*ldc (pass Kc=K, grid.z=1 for no split).
template <int ACT, int A_F32>
__global__ __launch_bounds__(256) void gemm_bt_mfma(
    const void* __restrict__ Aptr, const unsigned short* __restrict__ BT,
    float* __restrict__ C, const float* __restrict__ bias,
    int M, int N, int K, int lda, int ldb, int ldc, int Kc)
{
    __shared__ unsigned short As[128 * 40];
    __shared__ unsigned short Bs[128 * 40];

    const int tid  = threadIdx.x;
    const int lane = tid & 63;
    const int wave = tid >> 6;
    const int wm   = wave >> 1;               // 0..1
    const int wn   = wave & 1;
    const int row0 = blockIdx.y * 128;
    const int col0 = blockIdx.x * 128;
    const int lq   = lane >> 4;               // quad 0..3
    const int lm   = lane & 15;
    const int kbeg = blockIdx.z * Kc;

    float* Cz = C + (size_t)blockIdx.z * (size_t)M * ldc;

    f32x4 acc[4][4];
    #pragma unroll
    for (int i = 0; i < 4; i++)
        #pragma unroll
        for (int j = 0; j < 4; j++)
            #pragma unroll
            for (int r = 0; r < 4; r++) acc[i][j][r] = 0.0f;

    for (int k0 = kbeg; k0 < kbeg + Kc; k0 += 32) {
        #pragma unroll
        for (int it = 0; it < 2; it++) {
            int idx = (tid + it * 256) * 8;
            int r   = idx >> 5;               // 0..127
            int kk  = idx & 31;
            Pack8 p;
            if (A_F32) {
                const float* Af = (const float*)Aptr + (row0 + r) * lda + k0 + kk;
                float4 f0 = *(const float4*)Af;
                float4 f1 = *(const float4*)(Af + 4);
                p.s[0] = f2bf(f0.x); p.s[1] = f2bf(f0.y);
                p.s[2] = f2bf(f0.z); p.s[3] = f2bf(f0.w);
                p.s[4] = f2bf(f1.x); p.s[5] = f2bf(f1.y);
                p.s[6] = f2bf(f1.z); p.s[7] = f2bf(f1.w);
            } else {
                p.v = *(const uint4*)((const unsigned short*)Aptr +
                                      (row0 + r) * lda + k0 + kk);
            }
            *(uint4*)&As[r * 40 + kk] = p.v;
        }
        #pragma unroll
        for (int it = 0; it < 2; it++) {
            int idx = (tid + it * 256) * 8;
            int r   = idx >> 5;
            int kk  = idx & 31;
            uint4 raw = {0u, 0u, 0u, 0u};
            if (col0 + r < N)
                raw = *(const uint4*)(BT + (col0 + r) * ldb + k0 + kk);
            *(uint4*)&Bs[r * 40 + kk] = raw;
        }
        __syncthreads();

        bf16x8 af[4], bf[4];
        #pragma unroll
        for (int i = 0; i < 4; i++)
            af[i] = *(const bf16x8*)&As[(wm * 64 + i * 16 + lm) * 40 + lq * 8];
        #pragma unroll
        for (int j = 0; j < 4; j++)
            bf[j] = *(const bf16x8*)&Bs[(wn * 64 + j * 16 + lm) * 40 + lq * 8];
        #pragma unroll
        for (int i = 0; i < 4; i++)
            #pragma unroll
            for (int j = 0; j < 4; j++)
                acc[i][j] = __builtin_amdgcn_mfma_f32_16x16x32_bf16(
                    af[i], bf[j], acc[i][j], 0, 0, 0);
        __syncthreads();
    }

    // epilogue: C/D layout col=lane&15, row=(lane>>4)*4+reg
    #pragma unroll
    for (int i = 0; i < 4; i++) {
        #pragma unroll
        for (int r = 0; r < 4; r++) {
            int row = row0 + wm * 64 + i * 16 + lq * 4 + r;
            #pragma unroll
            for (int j = 0; j < 4; j++) {
                int col = col0 + wn * 64 + j * 16 + lm;
                if (col < N) {
                    float v = acc[i][j][r];
                    if (ACT == 1) v = softplus_f(v + bias[col]);
                    Cz[row * ldc + col] = v;
                }
            }
        }
    }
}

// Sum nsplit partial C buffers (deterministic split-K reduction).
__global__ __launch_bounds__(256) void reduce_splitk(
    const float* __restrict__ part, float* __restrict__ C, int n, int nsplit)
{
    int i = blockIdx.x * 256 + threadIdx.x;
    if (i >= n) return;
    float s = 0.0f;
    for (int z = 0; z < nsplit; z++) s += part[(size_t)z * n + i];
    C[i] = s;
}

__global__ __launch_bounds__(256) void conv_silu_kernel(
    const float* __restrict__ xz, const float* __restrict__ conv_w,
    const float* __restrict__ conv_b, float* __restrict__ xc)
{
    int idx = blockIdx.x * 256 + threadIdx.x;
    if (idx >= B_SZ * L_SZ * DINNER) return;
    int d  = idx & (DINNER - 1);
    int bl = idx >> 11;
    int l  = bl & (L_SZ - 1);
    float acc = conv_b[d];
    #pragma unroll
    for (int k = 0; k < DCONV; k++) {
        int ls = l - (DCONV - 1) + k;
        if (ls >= 0) acc += xz[(bl - (DCONV - 1) + k) * 4096 + d] * conv_w[d * DCONV + k];
    }
    xc[idx] = silu_f(acc);
}

// ---- Chunked parallel selective scan ----------------------------------------
__global__ __launch_bounds__(256) void scan_pass1(
    const float* __restrict__ xc, const float* __restrict__ delta,
    const float* __restrict__ dbc, const float* __restrict__ A_log,
    float* __restrict__ P, float* __restrict__ E)
{
    __shared__ float Bs[CS * DSTATE];
    const int tid = threadIdx.x;
    const int db  = blockIdx.x & 7;
    const int c   = (blockIdx.x >> 3) & (NCH - 1);
    const int b   = blockIdx.x >> 8;
    const int d   = db * 256 + tid;
    const int t0  = b * L_SZ + c * CS;

    for (int idx = tid; idx < CS * DSTATE; idx += 256) {
        int step = idx >> 4, i = idx & 15;
        Bs[idx] = dbc[(t0 + step) * 96 + DTRANK + i];
    }

    float A[DSTATE], Pr[DSTATE], Er[DSTATE];
    #pragma unroll
    for (int s = 0; s < DSTATE; s++) {
        A[s]  = -__expf(A_log[d * DSTATE + s]);
        Pr[s] = 1.0f;
        Er[s] = 0.0f;
    }
    __syncthreads();

    for (int l = 0; l < CS; l++) {
        const int t = t0 + l;
        float dv = delta[t * DINNER + d];
        float uv = xc[t * DINNER + d];
        float du = dv * uv;
        #pragma unroll
        for (int s = 0; s < DSTATE; s++) {
            float dA = __expf(dv * A[s]);
            Pr[s] *= dA;
            Er[s] = dA * Er[s] + du * Bs[l * DSTATE + s];
        }
    }

    const long long o = ((long long)((b * NCH + c) * DINNER) + d) * DSTATE;
    #pragma unroll
    for (int s = 0; s < DSTATE; s++) {
        P[o + s] = Pr[s];
        E[o + s] = Er[s];
    }
}

__global__ __launch_bounds__(256) void scan_pass2(
    const float* __restrict__ P, float* __restrict__ E)
{
    const int gid  = blockIdx.x * 256 + threadIdx.x;
    const int b    = gid >> 15;
    const int rest = gid & 32767;
    float h = 0.0f;
    for (int c = 0; c < NCH; c++) {
        const long long idx = (long long)(b * NCH + c) * (DINNER * DSTATE) + rest;
        float p = P[idx];
        float e = E[idx];
        E[idx] = h;
        h = p * h + e;
    }
}

// pass3: emit y in bf16 (A-operand of the out GEMM), fused silu(z) gate.
__global__ __launch_bounds__(256) void scan_pass3(
    const float* __restrict__ xc, const float* __restrict__ delta,
    const float* __restrict__ dbc, const float* __restrict__ A_log,
    const float* __restrict__ D_skip, const float* __restrict__ Hin,
    const float* __restrict__ xz, unsigned short* __restrict__ y16)
{
    __shared__ float BCs[CS * 2 * DSTATE];
    const int tid = threadIdx.x;
    const int db  = blockIdx.x & 7;
    const int c   = (blockIdx.x >> 3) & (NCH - 1);
    const int b   = blockIdx.x >> 8;
    const int d   = db * 256 + tid;
    const int t0  = b * L_SZ + c * CS;

    for (int idx = tid; idx < CS * 2 * DSTATE; idx += 256) {
        int step = idx >> 5, i = idx & 31;
        BCs[idx] = dbc[(t0 + step) * 96 + DTRANK + i];
    }

    float A[DSTATE], h[DSTATE];
    const long long o = ((long long)((b * NCH + c) * DINNER) + d) * DSTATE;
    #pragma unroll
    for (int s = 0; s < DSTATE; s++) {
        A[s] = -__expf(A_log[d * DSTATE + s]);
        h[s] = Hin[o + s];
    }
    const float Dv = D_skip[d];
    __syncthreads();

    for (int l = 0; l < CS; l++) {
        const int t = t0 + l;
        float dv = delta[t * DINNER + d];
        float uv = xc[t * DINNER + d];
        float du = dv * uv;
        float yv = 0.0f;
        #pragma unroll
        for (int s = 0; s < DSTATE; s++) {
            float dA = __expf(dv * A[s]);
            h[s] = dA * h[s] + du * BCs[l * 32 + s];
            yv  += h[s] * BCs[l * 32 + DSTATE + s];
        }
        float z = xz[t * 4096 + DINNER + d];
        y16[t * DINNER + d] = f2bf((uv * Dv + yv) * silu_f(z));
    }
}

extern "C" void kernel_launch(void* const* d_in, const int* in_sizes, int n_in,
                              void* d_out, int out_size, void* d_ws, size_t ws_size,
                              hipStream_t stream) {
    const float* x       = (const float*)d_in[0];
    const float* W_in    = (const float*)d_in[1];
    const float* conv_w  = (const float*)d_in[2];
    const float* conv_b  = (const float*)d_in[3];
    const float* W_xproj = (const float*)d_in[4];
    const float* W_dt    = (const float*)d_in[5];
    const float* b_dt    = (const float*)d_in[6];
    const float* A_log   = (const float*)d_in[7];
    const float* D_skip  = (const float*)d_in[8];
    const float* W_out   = (const float*)d_in[9];
    float* out = (float*)d_out;

    // workspace layout (floats) — ~165.5 MB total
    float* ws      = (float*)d_ws;
    float* xz      = ws;                         // 16777216
    float* xc      = xz    + 16777216;           //  8388608
    float* dbc     = xc    +  8388608;           //   393216
    float* delta   = dbc   +   393216;           //  8388608
    float* Ebuf    = delta +  8388608;           //  2097152  (becomes Hin)
    float* regionF = Ebuf  +  2097152;           //  4194304 f multi-use:
    //   [gemm1]      W_inT   = regionF[0 .. 2097152) as shorts (4194304 s)
    //   [gemm3]      parts   = regionF[0 .. 3145728)  (8 x 4096 x 96)
    //   [scan1/2]    Pbuf    = regionF[2097152 .. 4194304)
    //   [pass3/gemm6] yb16   = regionF[0 .. 2097152) as shorts
    unsigned short* W_inT = (unsigned short*)regionF;
    float* parts   = regionF;
    float* Pbuf    = regionF + 2097152;
    unsigned short* yb16  = (unsigned short*)regionF;
    unsigned short* W_xprojT = (unsigned short*)(regionF + 4194304); // 196608 s
    unsigned short* W_dtT    = W_xprojT + 196608;                    // 131072 s
    unsigned short* W_outT   = W_dtT    + 131072;                    // 2097152 s

    const int MT = 4096;  // B*L tokens

    // weight transposes + casts (bf16, B^T layout)
    transpose_cast<<<dim3(128, 32), 256, 0, stream>>>(W_in,    W_inT,    1024, 4096);
    transpose_cast<<<dim3(  3, 64), 256, 0, stream>>>(W_xproj, W_xprojT, 2048,   96);
    transpose_cast<<<dim3( 64,  2), 256, 0, stream>>>(W_dt,    W_dtT,      64, 2048);
    transpose_cast<<<dim3( 32, 64), 256, 0, stream>>>(W_out,   W_outT,   2048, 1024);

    // 1) xz = x @ W_in              (4096 x 4096, K=1024)
    gemm_bt_mfma<0, 1><<<dim3(32, 32), 256, 0, stream>>>(
        x, W_inT, xz, nullptr, MT, 4096, 1024, 1024, 1024, 4096, 1024);

    // 2) xc = silu(causal_dwconv(xin) + b)
    conv_silu_kernel<<<dim3(32768), 256, 0, stream>>>(xz, conv_w, conv_b, xc);

    // 3) dbc = xc @ W_xproj         (4096 x 96, K=2048) — split-K x8
    gemm_bt_mfma<0, 1><<<dim3(1, 32, 8), 256, 0, stream>>>(
        xc, W_xprojT, parts, nullptr, MT, 96, 2048, 2048, 2048, 96, 256);
    reduce_splitk<<<dim3(1536), 256, 0, stream>>>(parts, dbc, MT * 96, 8);

    // 4) delta = softplus(dt_lo @ W_dt + b_dt)  (4096 x 2048, K=64)
    gemm_bt_mfma<1, 1><<<dim3(16, 32), 256, 0, stream>>>(
        dbc, W_dtT, delta, b_dt, MT, 2048, 64, 96, 64, 2048, 64);

    // 5) chunked selective scan + fused gate (bf16 y out)
    scan_pass1<<<dim3(512), 256, 0, stream>>>(xc, delta, dbc, A_log, Pbuf, Ebuf);
    scan_pass2<<<dim3(256), 256, 0, stream>>>(Pbuf, Ebuf);
    scan_pass3<<<dim3(512), 256, 0, stream>>>(xc, delta, dbc, A_log, D_skip,
                                              Ebuf, xz, yb16);

    // 6) out = y @ W_out            (4096 x 1024, K=2048)
    gemm_bt_mfma<0, 0><<<dim3(8, 32), 256, 0, stream>>>(
        yb16, W_outT, out, nullptr, MT, 1024, 2048, 2048, 2048, 1024, 2048);
}

// Round 5
// 417.419 us; speedup vs baseline: 10.3274x; 1.0814x over previous
//
#include <hip/hip_runtime.h>
#include <math.h>

#define B_SZ 2
#define L_SZ 2048
#define DMODEL 1024
#define DINNER 2048
#define DSTATE 16
#define DCONV 4
#define DTRANK 64

#define CS 64                    // scan chunk size
#define NCH (L_SZ / CS)          // 32 chunks per batch

typedef float f32x4 __attribute__((ext_vector_type(4)));
typedef __bf16 bf16x8 __attribute__((ext_vector_type(8)));

__device__ __forceinline__ float silu_f(float x) {
    return x / (1.0f + __expf(-x));
}

__device__ __forceinline__ float softplus_f(float x) {
    return (x > 20.0f) ? x : log1pf(expf(x));   // keep precise: feeds exp in scan
}

// fp32 -> bf16 round-to-nearest-even on raw bits
__device__ __forceinline__ unsigned short f2bf(float x) {
    unsigned int u = __float_as_uint(x);
    u = u + 0x7FFFu + ((u >> 16) & 1u);
    return (unsigned short)(u >> 16);
}

// async global->LDS DMA, 16B per lane. lds dest must be wave-uniform base;
// HW deposits at base + lane*16B.
__device__ __forceinline__ void gload_lds16(const unsigned short* g, unsigned short* l) {
    __builtin_amdgcn_global_load_lds(
        (const __attribute__((address_space(1))) void*)g,
        (__attribute__((address_space(3))) void*)l, 16, 0, 0);
}

union Pack8 { unsigned short s[8]; uint4 v; };

// Transpose + cast: W[R,C] fp32 -> WT[C,R] bf16. Grid (C/32, R/32), 256 thr.
__global__ __launch_bounds__(256) void transpose_cast(
    const float* __restrict__ W, unsigned short* __restrict__ WT, int R, int C)
{
    __shared__ float t[32][33];
    const int tx = threadIdx.x & 31;
    const int ty = threadIdx.x >> 5;          // 0..7
    const int r0 = blockIdx.y * 32;
    const int c0 = blockIdx.x * 32;
    #pragma unroll
    for (int i = 0; i < 4; i++)
        t[ty + i * 8][tx] = W[(r0 + ty + i * 8) * C + c0 + tx];
    __syncthreads();
    #pragma unroll
    for (int i = 0; i < 4; i++)
        WT[(c0 + ty + i * 8) * R + r0 + tx] = f2bf(t[tx][ty + i * 8]);
}

// cast fp32 -> bf16, 8 elems/thread
__global__ __launch_bounds__(256) void cast_bf16(
    const float* __restrict__ src, unsigned short* __restrict__ dst, int n8)
{
    int i = blockIdx.x * 256 + threadIdx.x;
    if (i >= n8) return;
    const float4 f0 = *(const float4*)(src + i * 8);
    const float4 f1 = *(const float4*)(src + i * 8 + 4);
    Pack8 p;
    p.s[0] = f2bf(f0.x); p.s[1] = f2bf(f0.y); p.s[2] = f2bf(f0.z); p.s[3] = f2bf(f0.w);
    p.s[4] = f2bf(f1.x); p.s[5] = f2bf(f1.y); p.s[6] = f2bf(f1.z); p.s[7] = f2bf(f1.w);
    *(uint4*)(dst + i * 8) = p.v;
}

// ---- bf16 MFMA GEMM, B pre-transposed, global_load_lds staging (m97) -------
// C[M,N](fp32) = A[M,K](bf16) @ BT[N,K](bf16)^T, fp32 accumulate.
// Tile 128x128, BK=32, 4 waves (2x2), 64x64/wave via mfma_f32_16x16x32_bf16.
// LDS tiles are UNPADDED [128][32] shorts (lane order == LDS order, required
// by global_load_lds wave-uniform-base semantics). Split-K via gridDim.z.
// B tile row index is clamped to N-1 (over-read cols are discarded in the
// epilogue), so N need not be a multiple of 128.
__global__ __launch_bounds__(256) void gemm_bt_lds(
    const unsigned short* __restrict__ A, const unsigned short* __restrict__ BT,
    float* __restrict__ C, int M, int N, int K,
    int lda, int ldb, int ldc, int Kc)
{
    __shared__ unsigned short As[128 * 32];
    __shared__ unsigned short Bs[128 * 32];

    const int tid  = threadIdx.x;
    const int lane = tid & 63;
    const int wave = tid >> 6;
    const int wm   = wave >> 1;
    const int wn   = wave & 1;
    const int row0 = blockIdx.y * 128;
    const int col0 = blockIdx.x * 128;
    const int lq   = lane >> 4;
    const int lm   = lane & 15;
    const int kbeg = blockIdx.z * Kc;

    float* Cz = C + (size_t)blockIdx.z * (size_t)M * ldc;

    // staging geometry: each wave owns 32 rows of each tile (2 issues x 16 rows)
    const int sr = wave * 32 + (lane >> 2);           // tile row, first issue
    const int sk = (lane & 3) * 8;                    // k offset (shorts)
    const unsigned short* gA1 = A + (size_t)(row0 + sr) * lda + sk;
    const unsigned short* gA2 = gA1 + (size_t)16 * lda;
    int br1 = col0 + sr;      if (br1 > N - 1) br1 = N - 1;
    int br2 = col0 + sr + 16; if (br2 > N - 1) br2 = N - 1;
    const unsigned short* gB1 = BT + (size_t)br1 * ldb + sk;
    const unsigned short* gB2 = BT + (size_t)br2 * ldb + sk;
    unsigned short* lA1 = As + wave * 1024;           // wave-uniform bases
    unsigned short* lA2 = lA1 + 512;
    unsigned short* lB1 = Bs + wave * 1024;
    unsigned short* lB2 = lB1 + 512;

    f32x4 acc[4][4];
    #pragma unroll
    for (int i = 0; i < 4; i++)
        #pragma unroll
        for (int j = 0; j < 4; j++)
            #pragma unroll
            for (int r = 0; r < 4; r++) acc[i][j][r] = 0.0f;

    for (int k0 = kbeg; k0 < kbeg + Kc; k0 += 32) {
        gload_lds16(gA1 + k0, lA1);
        gload_lds16(gA2 + k0, lA2);
        gload_lds16(gB1 + k0, lB1);
        gload_lds16(gB2 + k0, lB2);
        __syncthreads();   // drains vmcnt (compiler inserts the waitcnt)

        bf16x8 af[4], bfr[4];
        #pragma unroll
        for (int i = 0; i < 4; i++)
            af[i] = *(const bf16x8*)&As[(wm * 64 + i * 16 + lm) * 32 + lq * 8];
        #pragma unroll
        for (int j = 0; j < 4; j++)
            bfr[j] = *(const bf16x8*)&Bs[(wn * 64 + j * 16 + lm) * 32 + lq * 8];
        #pragma unroll
        for (int i = 0; i < 4; i++)
            #pragma unroll
            for (int j = 0; j < 4; j++)
                acc[i][j] = __builtin_amdgcn_mfma_f32_16x16x32_bf16(
                    af[i], bfr[j], acc[i][j], 0, 0, 0);
        __syncthreads();
    }

    // epilogue: C/D layout col=lane&15, row=(lane>>4)*4+reg
    #pragma unroll
    for (int i = 0; i < 4; i++) {
        #pragma unroll
        for (int r = 0; r < 4; r++) {
            int row = row0 + wm * 64 + i * 16 + lq * 4 + r;
            #pragma unroll
            for (int j = 0; j < 4; j++) {
                int col = col0 + wn * 64 + j * 16 + lm;
                if (col < N) Cz[row * ldc + col] = acc[i][j][r];
            }
        }
    }
}

// ---- legacy path (fp32 A inline-converted): used only for the K=64 delta GEMM
template <int ACT, int A_F32>
__global__ __launch_bounds__(256) void gemm_bt_mfma(
    const void* __restrict__ Aptr, const unsigned short* __restrict__ BT,
    float* __restrict__ C, const float* __restrict__ bias,
    int M, int N, int K, int lda, int ldb, int ldc, int Kc)
{
    __shared__ unsigned short As[128 * 40];
    __shared__ unsigned short Bs[128 * 40];

    const int tid  = threadIdx.x;
    const int lane = tid & 63;
    const int wave = tid >> 6;
    const int wm   = wave >> 1;
    const int wn   = wave & 1;
    const int row0 = blockIdx.y * 128;
    const int col0 = blockIdx.x * 128;
    const int lq   = lane >> 4;
    const int lm   = lane & 15;
    const int kbeg = blockIdx.z * Kc;

    float* Cz = C + (size_t)blockIdx.z * (size_t)M * ldc;

    f32x4 acc[4][4];
    #pragma unroll
    for (int i = 0; i < 4; i++)
        #pragma unroll
        for (int j = 0; j < 4; j++)
            #pragma unroll
            for (int r = 0; r < 4; r++) acc[i][j][r] = 0.0f;

    for (int k0 = kbeg; k0 < kbeg + Kc; k0 += 32) {
        #pragma unroll
        for (int it = 0; it < 2; it++) {
            int idx = (tid + it * 256) * 8;
            int r   = idx >> 5;
            int kk  = idx & 31;
            Pack8 p;
            if (A_F32) {
                const float* Af = (const float*)Aptr + (row0 + r) * lda + k0 + kk;
                float4 f0 = *(const float4*)Af;
                float4 f1 = *(const float4*)(Af + 4);
                p.s[0] = f2bf(f0.x); p.s[1] = f2bf(f0.y);
                p.s[2] = f2bf(f0.z); p.s[3] = f2bf(f0.w);
                p.s[4] = f2bf(f1.x); p.s[5] = f2bf(f1.y);
                p.s[6] = f2bf(f1.z); p.s[7] = f2bf(f1.w);
            } else {
                p.v = *(const uint4*)((const unsigned short*)Aptr +
                                      (row0 + r) * lda + k0 + kk);
            }
            *(uint4*)&As[r * 40 + kk] = p.v;
        }
        #pragma unroll
        for (int it = 0; it < 2; it++) {
            int idx = (tid + it * 256) * 8;
            int r   = idx >> 5;
            int kk  = idx & 31;
            uint4 raw = {0u, 0u, 0u, 0u};
            if (col0 + r < N)
                raw = *(const uint4*)(BT + (col0 + r) * ldb + k0 + kk);
            *(uint4*)&Bs[r * 40 + kk] = raw;
        }
        __syncthreads();

        bf16x8 af[4], bfr[4];
        #pragma unroll
        for (int i = 0; i < 4; i++)
            af[i] = *(const bf16x8*)&As[(wm * 64 + i * 16 + lm) * 40 + lq * 8];
        #pragma unroll
        for (int j = 0; j < 4; j++)
            bfr[j] = *(const bf16x8*)&Bs[(wn * 64 + j * 16 + lm) * 40 + lq * 8];
        #pragma unroll
        for (int i = 0; i < 4; i++)
            #pragma unroll
            for (int j = 0; j < 4; j++)
                acc[i][j] = __builtin_amdgcn_mfma_f32_16x16x32_bf16(
                    af[i], bfr[j], acc[i][j], 0, 0, 0);
        __syncthreads();
    }

    #pragma unroll
    for (int i = 0; i < 4; i++) {
        #pragma unroll
        for (int r = 0; r < 4; r++) {
            int row = row0 + wm * 64 + i * 16 + lq * 4 + r;
            #pragma unroll
            for (int j = 0; j < 4; j++) {
                int col = col0 + wn * 64 + j * 16 + lm;
                if (col < N) {
                    float v = acc[i][j][r];
                    if (ACT == 1) v = softplus_f(v + bias[col]);
                    Cz[row * ldc + col] = v;
                }
            }
        }
    }
}

// Sum nsplit partial C buffers (deterministic split-K reduction).
__global__ __launch_bounds__(256) void reduce_splitk(
    const float* __restrict__ part, float* __restrict__ C, int n, int nsplit)
{
    int i = blockIdx.x * 256 + threadIdx.x;
    if (i >= n) return;
    float s = 0.0f;
    for (int z = 0; z < nsplit; z++) s += part[(size_t)z * n + i];
    C[i] = s;
}

// conv + silu; emits fp32 (for the scan) and bf16 (GEMM A-operand)
__global__ __launch_bounds__(256) void conv_silu_kernel(
    const float* __restrict__ xz, const float* __restrict__ conv_w,
    const float* __restrict__ conv_b, float* __restrict__ xc,
    unsigned short* __restrict__ xc16)
{
    int idx = blockIdx.x * 256 + threadIdx.x;
    if (idx >= B_SZ * L_SZ * DINNER) return;
    int d  = idx & (DINNER - 1);
    int bl = idx >> 11;
    int l  = bl & (L_SZ - 1);
    float acc = conv_b[d];
    #pragma unroll
    for (int k = 0; k < DCONV; k++) {
        int ls = l - (DCONV - 1) + k;
        if (ls >= 0) acc += xz[(bl - (DCONV - 1) + k) * 4096 + d] * conv_w[d * DCONV + k];
    }
    float v = silu_f(acc);
    xc[idx] = v;
    xc16[idx] = f2bf(v);
}

// ---- Chunked parallel selective scan ----------------------------------------
__global__ __launch_bounds__(256) void scan_pass1(
    const float* __restrict__ xc, const float* __restrict__ delta,
    const float* __restrict__ dbc, const float* __restrict__ A_log,
    float* __restrict__ P, float* __restrict__ E)
{
    __shared__ float Bs[CS * DSTATE];
    const int tid = threadIdx.x;
    const int db  = blockIdx.x & 7;
    const int c   = (blockIdx.x >> 3) & (NCH - 1);
    const int b   = blockIdx.x >> 8;
    const int d   = db * 256 + tid;
    const int t0  = b * L_SZ + c * CS;

    for (int idx = tid; idx < CS * DSTATE; idx += 256) {
        int step = idx >> 4, i = idx & 15;
        Bs[idx] = dbc[(t0 + step) * 96 + DTRANK + i];
    }

    float A[DSTATE], Pr[DSTATE], Er[DSTATE];
    #pragma unroll
    for (int s = 0; s < DSTATE; s++) {
        A[s]  = -__expf(A_log[d * DSTATE + s]);
        Pr[s] = 1.0f;
        Er[s] = 0.0f;
    }
    __syncthreads();

    for (int l = 0; l < CS; l++) {
        const int t = t0 + l;
        float dv = delta[t * DINNER + d];
        float uv = xc[t * DINNER + d];
        float du = dv * uv;
        #pragma unroll
        for (int s = 0; s < DSTATE; s++) {
            float dA = __expf(dv * A[s]);
            Pr[s] *= dA;
            Er[s] = dA * Er[s] + du * Bs[l * DSTATE + s];
        }
    }

    const long long o = ((long long)((b * NCH + c) * DINNER) + d) * DSTATE;
    #pragma unroll
    for (int s = 0; s < DSTATE; s++) {
        P[o + s] = Pr[s];
        E[o + s] = Er[s];
    }
}

__global__ __launch_bounds__(256) void scan_pass2(
    const float* __restrict__ P, float* __restrict__ E)
{
    const int gid  = blockIdx.x * 256 + threadIdx.x;
    const int b    = gid >> 15;
    const int rest = gid & 32767;
    float h = 0.0f;
    for (int c = 0; c < NCH; c++) {
        const long long idx = (long long)(b * NCH + c) * (DINNER * DSTATE) + rest;
        float p = P[idx];
        float e = E[idx];
        E[idx] = h;
        h = p * h + e;
    }
}

// pass3: emit y in bf16 (A-operand of the out GEMM), fused silu(z) gate.
__global__ __launch_bounds__(256) void scan_pass3(
    const float* __restrict__ xc, const float* __restrict__ delta,
    const float* __restrict__ dbc, const float* __restrict__ A_log,
    const float* __restrict__ D_skip, const float* __restrict__ Hin,
    const float* __restrict__ xz, unsigned short* __restrict__ y16)
{
    __shared__ float BCs[CS * 2 * DSTATE];
    const int tid = threadIdx.x;
    const int db  = blockIdx.x & 7;
    const int c   = (blockIdx.x >> 3) & (NCH - 1);
    const int b   = blockIdx.x >> 8;
    const int d   = db * 256 + tid;
    const int t0  = b * L_SZ + c * CS;

    for (int idx = tid; idx < CS * 2 * DSTATE; idx += 256) {
        int step = idx >> 5, i = idx & 31;
        BCs[idx] = dbc[(t0 + step) * 96 + DTRANK + i];
    }

    float A[DSTATE], h[DSTATE];
    const long long o = ((long long)((b * NCH + c) * DINNER) + d) * DSTATE;
    #pragma unroll
    for (int s = 0; s < DSTATE; s++) {
        A[s] = -__expf(A_log[d * DSTATE + s]);
        h[s] = Hin[o + s];
    }
    const float Dv = D_skip[d];
    __syncthreads();

    for (int l = 0; l < CS; l++) {
        const int t = t0 + l;
        float dv = delta[t * DINNER + d];
        float uv = xc[t * DINNER + d];
        float du = dv * uv;
        float yv = 0.0f;
        #pragma unroll
        for (int s = 0; s < DSTATE; s++) {
            float dA = __expf(dv * A[s]);
            h[s] = dA * h[s] + du * BCs[l * 32 + s];
            yv  += h[s] * BCs[l * 32 + DSTATE + s];
        }
        float z = xz[t * 4096 + DINNER + d];
        y16[t * DINNER + d] = f2bf((uv * Dv + yv) * silu_f(z));
    }
}

extern "C" void kernel_launch(void* const* d_in, const int* in_sizes, int n_in,
                              void* d_out, int out_size, void* d_ws, size_t ws_size,
                              hipStream_t stream) {
    const float* x       = (const float*)d_in[0];
    const float* W_in    = (const float*)d_in[1];
    const float* conv_w  = (const float*)d_in[2];
    const float* conv_b  = (const float*)d_in[3];
    const float* W_xproj = (const float*)d_in[4];
    const float* W_dt    = (const float*)d_in[5];
    const float* b_dt    = (const float*)d_in[6];
    const float* A_log   = (const float*)d_in[7];
    const float* D_skip  = (const float*)d_in[8];
    const float* W_out   = (const float*)d_in[9];
    float* out = (float*)d_out;

    // workspace layout (floats) — ~166 MB total
    float* ws      = (float*)d_ws;
    float* xz      = ws;                         // 16777216
    float* xc      = xz    + 16777216;           //  8388608
    float* dbc     = xc    +  8388608;           //   393216
    float* delta   = dbc   +   393216;           //  8388608 — early phases reuse:
    //   x16  = delta[0 .. 2097152) as shorts  (dead after gemm1)
    //   xc16 = delta[2097152 .. 6291456) as shorts (written step2, dead after gemm3)
    float* Ebuf    = delta +  8388608;           //  2097152  (becomes Hin)
    float* regionF = Ebuf  +  2097152;           //  4194304 f multi-use:
    //   [gemm1]       W_inT = regionF[0..2097152) as shorts
    //   [gemm3]       parts = regionF[0..3145728)
    //   [scan1/2]     Pbuf  = regionF[2097152..4194304)
    //   [pass3/gemm6] yb16  = regionF[0..2097152) as shorts
    unsigned short* x16   = (unsigned short*)delta;
    unsigned short* xc16  = (unsigned short*)(delta + 2097152);
    unsigned short* W_inT = (unsigned short*)regionF;
    float* parts   = regionF;
    float* Pbuf    = regionF + 2097152;
    unsigned short* yb16  = (unsigned short*)regionF;
    unsigned short* W_xprojT = (unsigned short*)(regionF + 4194304); // 196608 s
    unsigned short* W_dtT    = W_xprojT + 196608;                    // 131072 s
    unsigned short* W_outT   = W_dtT    + 131072;                    // 2097152 s

    const int MT = 4096;  // B*L tokens

    // weight transposes + casts (bf16, B^T layout) + x cast
    transpose_cast<<<dim3(128, 32), 256, 0, stream>>>(W_in,    W_inT,    1024, 4096);
    transpose_cast<<<dim3(  3, 64), 256, 0, stream>>>(W_xproj, W_xprojT, 2048,   96);
    transpose_cast<<<dim3( 64,  2), 256, 0, stream>>>(W_dt,    W_dtT,      64, 2048);
    transpose_cast<<<dim3( 32, 64), 256, 0, stream>>>(W_out,   W_outT,   2048, 1024);
    cast_bf16<<<dim3(2048), 256, 0, stream>>>(x, x16, 524288);

    // 1) xz = x @ W_in              (4096 x 4096, K=1024)
    gemm_bt_lds<<<dim3(32, 32), 256, 0, stream>>>(
        x16, W_inT, xz, MT, 4096, 1024, 1024, 1024, 4096, 1024);

    // 2) xc/xc16 = silu(causal_dwconv(xin) + b)
    conv_silu_kernel<<<dim3(32768), 256, 0, stream>>>(xz, conv_w, conv_b, xc, xc16);

    // 3) dbc = xc @ W_xproj         (4096 x 96, K=2048) — split-K x8
    gemm_bt_lds<<<dim3(1, 32, 8), 256, 0, stream>>>(
        xc16, W_xprojT, parts, MT, 96, 2048, 2048, 2048, 96, 256);
    reduce_splitk<<<dim3(1536), 256, 0, stream>>>(parts, dbc, MT * 96, 8);

    // 4) delta = softplus(dt_lo @ W_dt + b_dt)  (4096 x 2048, K=64)
    gemm_bt_mfma<1, 1><<<dim3(16, 32), 256, 0, stream>>>(
        dbc, W_dtT, delta, b_dt, MT, 2048, 64, 96, 64, 2048, 64);

    // 5) chunked selective scan + fused gate (bf16 y out)
    scan_pass1<<<dim3(512), 256, 0, stream>>>(xc, delta, dbc, A_log, Pbuf, Ebuf);
    scan_pass2<<<dim3(256), 256, 0, stream>>>(Pbuf, Ebuf);
    scan_pass3<<<dim3(512), 256, 0, stream>>>(xc, delta, dbc, A_log, D_skip,
                                              Ebuf, xz, yb16);

    // 6) out = y @ W_out            (4096 x 1024, K=2048)
    gemm_bt_lds<<<dim3(8, 32), 256, 0, stream>>>(
        yb16, W_outT, out, MT, 1024, 2048, 2048, 2048, 1024, 2048);
}

// Round 6
// 379.340 us; speedup vs baseline: 11.3641x; 1.1004x over previous
//
#include <hip/hip_runtime.h>
#include <math.h>

#define B_SZ 2
#define L_SZ 2048
#define DMODEL 1024
#define DINNER 2048
#define DSTATE 16
#define DCONV 4
#define DTRANK 64

#define CS 64                    // scan chunk size
#define NCH (L_SZ / CS)          // 32 chunks per batch

typedef float f32x4 __attribute__((ext_vector_type(4)));
typedef __bf16 bf16x8 __attribute__((ext_vector_type(8)));

__device__ __forceinline__ float silu_f(float x) {
    return x / (1.0f + __expf(-x));
}

__device__ __forceinline__ float softplus_f(float x) {
    return (x > 20.0f) ? x : log1pf(expf(x));   // keep precise: feeds exp in scan
}

// fp32 -> bf16 round-to-nearest-even on raw bits
__device__ __forceinline__ unsigned short f2bf(float x) {
    unsigned int u = __float_as_uint(x);
    u = u + 0x7FFFu + ((u >> 16) & 1u);
    return (unsigned short)(u >> 16);
}

__device__ __forceinline__ float bf2f(unsigned short s) {
    return __uint_as_float(((unsigned int)s) << 16);
}

// async global->LDS DMA, 16B per lane. lds dest must be wave-uniform base;
// HW deposits at base + lane*16B.
__device__ __forceinline__ void gload_lds16(const unsigned short* g, unsigned short* l) {
    __builtin_amdgcn_global_load_lds(
        (const __attribute__((address_space(1))) void*)g,
        (__attribute__((address_space(3))) void*)l, 16, 0, 0);
}

union Pack8 { unsigned short s[8]; uint4 v; };

// Transpose + cast: W[R,C] fp32 -> WT[C,R] bf16. Grid (C/32, R/32), 256 thr.
__global__ __launch_bounds__(256) void transpose_cast(
    const float* __restrict__ W, unsigned short* __restrict__ WT, int R, int C)
{
    __shared__ float t[32][33];
    const int tx = threadIdx.x & 31;
    const int ty = threadIdx.x >> 5;          // 0..7
    const int r0 = blockIdx.y * 32;
    const int c0 = blockIdx.x * 32;
    #pragma unroll
    for (int i = 0; i < 4; i++)
        t[ty + i * 8][tx] = W[(r0 + ty + i * 8) * C + c0 + tx];
    __syncthreads();
    #pragma unroll
    for (int i = 0; i < 4; i++)
        WT[(c0 + ty + i * 8) * R + r0 + tx] = f2bf(t[tx][ty + i * 8]);
}

// cast fp32 -> bf16, 8 elems/thread
__global__ __launch_bounds__(256) void cast_bf16(
    const float* __restrict__ src, unsigned short* __restrict__ dst, int n8)
{
    int i = blockIdx.x * 256 + threadIdx.x;
    if (i >= n8) return;
    const float4 f0 = *(const float4*)(src + i * 8);
    const float4 f1 = *(const float4*)(src + i * 8 + 4);
    Pack8 p;
    p.s[0] = f2bf(f0.x); p.s[1] = f2bf(f0.y); p.s[2] = f2bf(f0.z); p.s[3] = f2bf(f0.w);
    p.s[4] = f2bf(f1.x); p.s[5] = f2bf(f1.y); p.s[6] = f2bf(f1.z); p.s[7] = f2bf(f1.w);
    *(uint4*)(dst + i * 8) = p.v;
}

// ---- bf16 MFMA GEMM, B pre-transposed, global_load_lds staging (m97) -------
// C[M,N] = A[M,K](bf16) @ BT[N,K](bf16)^T, fp32 accumulate.
// OBF16: output stored as bf16 (ldc in shorts) else fp32.
// ACT==1: C = softplus(C + bias[n]).
// Tile 128x128, BK=32, 4 waves (2x2), 64x64/wave via mfma_f32_16x16x32_bf16.
// LDS tiles UNPADDED [128][32] shorts (lane order == LDS order, required by
// global_load_lds). Split-K via gridDim.z. B row clamped to N-1 for N%128!=0.
template <int ACT, int OBF16>
__global__ __launch_bounds__(256) void gemm_bt_lds(
    const unsigned short* __restrict__ A, const unsigned short* __restrict__ BT,
    void* __restrict__ Cout, const float* __restrict__ bias,
    int M, int N, int K, int lda, int ldb, int ldc, int Kc)
{
    __shared__ unsigned short As[128 * 32];
    __shared__ unsigned short Bs[128 * 32];

    const int tid  = threadIdx.x;
    const int lane = tid & 63;
    const int wave = tid >> 6;
    const int wm   = wave >> 1;
    const int wn   = wave & 1;
    const int row0 = blockIdx.y * 128;
    const int col0 = blockIdx.x * 128;
    const int lq   = lane >> 4;
    const int lm   = lane & 15;
    const int kbeg = blockIdx.z * Kc;

    // staging geometry: each wave owns 32 rows of each tile (2 issues x 16 rows)
    const int sr = wave * 32 + (lane >> 2);           // tile row, first issue
    const int sk = (lane & 3) * 8;                    // k offset (shorts)
    const unsigned short* gA1 = A + (size_t)(row0 + sr) * lda + sk;
    const unsigned short* gA2 = gA1 + (size_t)16 * lda;
    int br1 = col0 + sr;      if (br1 > N - 1) br1 = N - 1;
    int br2 = col0 + sr + 16; if (br2 > N - 1) br2 = N - 1;
    const unsigned short* gB1 = BT + (size_t)br1 * ldb + sk;
    const unsigned short* gB2 = BT + (size_t)br2 * ldb + sk;
    unsigned short* lA1 = As + wave * 1024;           // wave-uniform bases
    unsigned short* lA2 = lA1 + 512;
    unsigned short* lB1 = Bs + wave * 1024;
    unsigned short* lB2 = lB1 + 512;

    f32x4 acc[4][4];
    #pragma unroll
    for (int i = 0; i < 4; i++)
        #pragma unroll
        for (int j = 0; j < 4; j++)
            #pragma unroll
            for (int r = 0; r < 4; r++) acc[i][j][r] = 0.0f;

    for (int k0 = kbeg; k0 < kbeg + Kc; k0 += 32) {
        gload_lds16(gA1 + k0, lA1);
        gload_lds16(gA2 + k0, lA2);
        gload_lds16(gB1 + k0, lB1);
        gload_lds16(gB2 + k0, lB2);
        __syncthreads();   // drains vmcnt (compiler inserts the waitcnt)

        bf16x8 af[4], bfr[4];
        #pragma unroll
        for (int i = 0; i < 4; i++)
            af[i] = *(const bf16x8*)&As[(wm * 64 + i * 16 + lm) * 32 + lq * 8];
        #pragma unroll
        for (int j = 0; j < 4; j++)
            bfr[j] = *(const bf16x8*)&Bs[(wn * 64 + j * 16 + lm) * 32 + lq * 8];
        #pragma unroll
        for (int i = 0; i < 4; i++)
            #pragma unroll
            for (int j = 0; j < 4; j++)
                acc[i][j] = __builtin_amdgcn_mfma_f32_16x16x32_bf16(
                    af[i], bfr[j], acc[i][j], 0, 0, 0);
        __syncthreads();
    }

    // epilogue: C/D layout col=lane&15, row=(lane>>4)*4+reg
    #pragma unroll
    for (int i = 0; i < 4; i++) {
        #pragma unroll
        for (int r = 0; r < 4; r++) {
            int row = row0 + wm * 64 + i * 16 + lq * 4 + r;
            #pragma unroll
            for (int j = 0; j < 4; j++) {
                int col = col0 + wn * 64 + j * 16 + lm;
                if (col < N) {
                    float v = acc[i][j][r];
                    if (ACT == 1) v = softplus_f(v + bias[col]);
                    if (OBF16) {
                        unsigned short* Cz = (unsigned short*)Cout +
                            (size_t)blockIdx.z * (size_t)M * ldc;
                        Cz[(size_t)row * ldc + col] = f2bf(v);
                    } else {
                        float* Cz = (float*)Cout +
                            (size_t)blockIdx.z * (size_t)M * ldc;
                        Cz[(size_t)row * ldc + col] = v;
                    }
                }
            }
        }
    }
}

// Sum nsplit partial C buffers; also emit bf16 copy of cols<64 (dt_lo) for
// the delta GEMM's A operand.
__global__ __launch_bounds__(256) void reduce_splitk(
    const float* __restrict__ part, float* __restrict__ C,
    unsigned short* __restrict__ dtlo16, int n, int nsplit)
{
    int i = blockIdx.x * 256 + threadIdx.x;
    if (i >= n) return;
    float s = 0.0f;
    for (int z = 0; z < nsplit; z++) s += part[(size_t)z * n + i];
    C[i] = s;
    int row = i / 96;
    int col = i - row * 96;
    if (col < DTRANK) dtlo16[row * DTRANK + col] = f2bf(s);
}

// conv + silu, register-rolling window along l. Reads bf16 xz (cols 0..2048),
// emits fp32 xc (scan) and bf16 xc16 (GEMM A-operand).
// grid (8, 64, 2): d-block, l-tile of 32, batch.
__global__ __launch_bounds__(256) void conv_silu_v2(
    const unsigned short* __restrict__ xz16, const float* __restrict__ conv_w,
    const float* __restrict__ conv_b, float* __restrict__ xc,
    unsigned short* __restrict__ xc16)
{
    const int tid = threadIdx.x;
    const int d   = blockIdx.x * 256 + tid;
    const int l0  = blockIdx.y * 32;
    const int b   = blockIdx.z;
    const float4 w  = *(const float4*)(conv_w + d * 4);
    const float bias = conv_b[d];
    const int t0 = b * L_SZ + l0;
    const unsigned short* src = xz16 + (size_t)t0 * 4096 + d;

    float r0, r1, r2;
    if (l0 == 0) {
        r0 = r1 = r2 = 0.0f;
    } else {
        r0 = bf2f(src[-3 * 4096]);
        r1 = bf2f(src[-2 * 4096]);
        r2 = bf2f(src[-1 * 4096]);
    }
    #pragma unroll 4
    for (int l = 0; l < 32; l++) {
        float r3 = bf2f(src[(size_t)l * 4096]);
        float acc = bias + r0 * w.x + r1 * w.y + r2 * w.z + r3 * w.w;
        float v = silu_f(acc);
        size_t o = (size_t)(t0 + l) * DINNER + d;
        xc[o] = v;
        xc16[o] = f2bf(v);
        r0 = r1; r1 = r2; r2 = r3;
    }
}

// ---- Chunked parallel selective scan ----------------------------------------
__global__ __launch_bounds__(256) void scan_pass1(
    const float* __restrict__ xc, const float* __restrict__ delta,
    const float* __restrict__ dbc, const float* __restrict__ A_log,
    float* __restrict__ P, float* __restrict__ E)
{
    __shared__ float Bs[CS * DSTATE];
    const int tid = threadIdx.x;
    const int db  = blockIdx.x & 7;
    const int c   = (blockIdx.x >> 3) & (NCH - 1);
    const int b   = blockIdx.x >> 8;
    const int d   = db * 256 + tid;
    const int t0  = b * L_SZ + c * CS;

    for (int idx = tid; idx < CS * DSTATE; idx += 256) {
        int step = idx >> 4, i = idx & 15;
        Bs[idx] = dbc[(t0 + step) * 96 + DTRANK + i];
    }

    float A[DSTATE], Er[DSTATE];
    #pragma unroll
    for (int s = 0; s < DSTATE; s++) {
        A[s]  = -__expf(A_log[d * DSTATE + s]);
        Er[s] = 0.0f;
    }
    float sd = 0.0f;
    __syncthreads();

    for (int l = 0; l < CS; l++) {
        const int t = t0 + l;
        float dv = delta[t * DINNER + d];
        float uv = xc[t * DINNER + d];
        float du = dv * uv;
        sd += dv;
        #pragma unroll
        for (int s = 0; s < DSTATE; s++) {
            float dA = __expf(dv * A[s]);
            Er[s] = dA * Er[s] + du * Bs[l * DSTATE + s];
        }
    }

    const long long o = ((long long)((b * NCH + c) * DINNER) + d) * DSTATE;
    #pragma unroll
    for (int s = 0; s < DSTATE; s++) {
        P[o + s] = __expf(A[s] * sd);   // == prod_l exp(dv_l * A[s])
        E[o + s] = Er[s];
    }
}

__global__ __launch_bounds__(256) void scan_pass2(
    const float* __restrict__ P, float* __restrict__ E)
{
    const int gid  = blockIdx.x * 256 + threadIdx.x;
    const int b    = gid >> 15;
    const int rest = gid & 32767;
    float h = 0.0f;
    for (int c = 0; c < NCH; c++) {
        const long long idx = (long long)(b * NCH + c) * (DINNER * DSTATE) + rest;
        float p = P[idx];
        float e = E[idx];
        E[idx] = h;
        h = p * h + e;
    }
}

// pass3: emit y in bf16 (A-operand of the out GEMM), fused silu(z) gate.
// z read from bf16 xz (cols 2048..4096).
__global__ __launch_bounds__(256) void scan_pass3(
    const float* __restrict__ xc, const float* __restrict__ delta,
    const float* __restrict__ dbc, const float* __restrict__ A_log,
    const float* __restrict__ D_skip, const float* __restrict__ Hin,
    const unsigned short* __restrict__ xz16, unsigned short* __restrict__ y16)
{
    __shared__ float BCs[CS * 2 * DSTATE];
    const int tid = threadIdx.x;
    const int db  = blockIdx.x & 7;
    const int c   = (blockIdx.x >> 3) & (NCH - 1);
    const int b   = blockIdx.x >> 8;
    const int d   = db * 256 + tid;
    const int t0  = b * L_SZ + c * CS;

    for (int idx = tid; idx < CS * 2 * DSTATE; idx += 256) {
        int step = idx >> 5, i = idx & 31;
        BCs[idx] = dbc[(t0 + step) * 96 + DTRANK + i];
    }

    float A[DSTATE], h[DSTATE];
    const long long o = ((long long)((b * NCH + c) * DINNER) + d) * DSTATE;
    #pragma unroll
    for (int s = 0; s < DSTATE; s++) {
        A[s] = -__expf(A_log[d * DSTATE + s]);
        h[s] = Hin[o + s];
    }
    const float Dv = D_skip[d];
    __syncthreads();

    for (int l = 0; l < CS; l++) {
        const int t = t0 + l;
        float dv = delta[t * DINNER + d];
        float uv = xc[t * DINNER + d];
        float du = dv * uv;
        float yv = 0.0f;
        #pragma unroll
        for (int s = 0; s < DSTATE; s++) {
            float dA = __expf(dv * A[s]);
            h[s] = dA * h[s] + du * BCs[l * 32 + s];
            yv  += h[s] * BCs[l * 32 + DSTATE + s];
        }
        float z = bf2f(xz16[(size_t)t * 4096 + DINNER + d]);
        y16[t * DINNER + d] = f2bf((uv * Dv + yv) * silu_f(z));
    }
}

extern "C" void kernel_launch(void* const* d_in, const int* in_sizes, int n_in,
                              void* d_out, int out_size, void* d_ws, size_t ws_size,
                              hipStream_t stream) {
    const float* x       = (const float*)d_in[0];
    const float* W_in    = (const float*)d_in[1];
    const float* conv_w  = (const float*)d_in[2];
    const float* conv_b  = (const float*)d_in[3];
    const float* W_xproj = (const float*)d_in[4];
    const float* W_dt    = (const float*)d_in[5];
    const float* b_dt    = (const float*)d_in[6];
    const float* A_log   = (const float*)d_in[7];
    const float* D_skip  = (const float*)d_in[8];
    const float* W_out   = (const float*)d_in[9];
    float* out = (float*)d_out;

    // workspace layout (float units) — ~154 MB total
    float* ws = (float*)d_ws;
    unsigned short* xz16 = (unsigned short*)ws;            // 16777216 s (8388608 f)
    float* xc    = ws + 8388608;                           //  8388608 f
    unsigned short* xc16 = (unsigned short*)(ws + 16777216); // 4194304 s (2097152 f)
    float* dbc   = ws + 18874368;                          //   393216 f
    unsigned short* dtlo16 = (unsigned short*)(ws + 19267584); // 262144 s (131072 f)
    float* delta = ws + 19398656;                          //  8388608 f
    float* Ebuf  = ws + 27787264;                          //  2097152 f (becomes Hin)
    float* parts = ws + 29884416;                          //  3145728 f (dead after reduce)
    float* Pbuf  = parts;                                  //  aliases parts
    unsigned short* x16  = (unsigned short*)(ws + 33030144); // 4194304 s (dead after gemm1)
    unsigned short* yb16 = x16;                            //  aliases x16
    unsigned short* W_inT    = (unsigned short*)(ws + 35127296); // 4194304 s
    unsigned short* W_xprojT = (unsigned short*)(ws + 37224448); //  196608 s
    unsigned short* W_dtT    = (unsigned short*)(ws + 37322752); //  131072 s
    unsigned short* W_outT   = (unsigned short*)(ws + 37388288); // 2097152 s

    const int MT = 4096;  // B*L tokens

    // weight transposes + casts (bf16, B^T layout) + x cast
    transpose_cast<<<dim3(128, 32), 256, 0, stream>>>(W_in,    W_inT,    1024, 4096);
    transpose_cast<<<dim3(  3, 64), 256, 0, stream>>>(W_xproj, W_xprojT, 2048,   96);
    transpose_cast<<<dim3( 64,  2), 256, 0, stream>>>(W_dt,    W_dtT,      64, 2048);
    transpose_cast<<<dim3( 32, 64), 256, 0, stream>>>(W_out,   W_outT,   2048, 1024);
    cast_bf16<<<dim3(2048), 256, 0, stream>>>(x, x16, 524288);

    // 1) xz = x @ W_in              (4096 x 4096, K=1024) -> bf16
    gemm_bt_lds<0, 1><<<dim3(32, 32), 256, 0, stream>>>(
        x16, W_inT, xz16, nullptr, MT, 4096, 1024, 1024, 1024, 4096, 1024);

    // 2) xc/xc16 = silu(causal_dwconv(xin) + b)
    conv_silu_v2<<<dim3(8, 64, 2), 256, 0, stream>>>(xz16, conv_w, conv_b, xc, xc16);

    // 3) dbc = xc @ W_xproj         (4096 x 96, K=2048) — split-K x8
    gemm_bt_lds<0, 0><<<dim3(1, 32, 8), 256, 0, stream>>>(
        xc16, W_xprojT, parts, nullptr, MT, 96, 2048, 2048, 2048, 96, 256);
    reduce_splitk<<<dim3(1536), 256, 0, stream>>>(parts, dbc, dtlo16, MT * 96, 8);

    // 4) delta = softplus(dt_lo @ W_dt + b_dt)  (4096 x 2048, K=64)
    gemm_bt_lds<1, 0><<<dim3(16, 32), 256, 0, stream>>>(
        dtlo16, W_dtT, delta, b_dt, MT, 2048, 64, 64, 64, 2048, 64);

    // 5) chunked selective scan + fused gate (bf16 y out)
    scan_pass1<<<dim3(512), 256, 0, stream>>>(xc, delta, dbc, A_log, Pbuf, Ebuf);
    scan_pass2<<<dim3(256), 256, 0, stream>>>(Pbuf, Ebuf);
    scan_pass3<<<dim3(512), 256, 0, stream>>>(xc, delta, dbc, A_log, D_skip,
                                              Ebuf, xz16, yb16);

    // 6) out = y @ W_out            (4096 x 1024, K=2048)
    gemm_bt_lds<0, 0><<<dim3(8, 32), 256, 0, stream>>>(
        yb16, W_outT, out, nullptr, MT, 1024, 2048, 2048, 2048, 1024, 2048);
}

// Round 9
// 365.280 us; speedup vs baseline: 11.8015x; 1.0385x over previous
//
#include <hip/hip_runtime.h>
#include <math.h>

#define B_SZ 2
#define L_SZ 2048
#define DMODEL 1024
#define DINNER 2048
#define DSTATE 16
#define DCONV 4
#define DTRANK 64

#define CS 64                    // scan chunk size
#define NCH (L_SZ / CS)          // 32 chunks per batch

typedef float f32x4 __attribute__((ext_vector_type(4)));
typedef __bf16 bf16x8 __attribute__((ext_vector_type(8)));

__device__ __forceinline__ float silu_f(float x) {
    return x / (1.0f + __expf(-x));
}

__device__ __forceinline__ float softplus_f(float x) {
    return (x > 20.0f) ? x : log1pf(expf(x));
}

// fp32 -> bf16 round-to-nearest-even on raw bits
__device__ __forceinline__ unsigned short f2bf(float x) {
    unsigned int u = __float_as_uint(x);
    u = u + 0x7FFFu + ((u >> 16) & 1u);
    return (unsigned short)(u >> 16);
}

__device__ __forceinline__ float bf2f(unsigned short s) {
    return __uint_as_float(((unsigned int)s) << 16);
}

// async global->LDS DMA, 16B per lane; deposits at base + lane*16B.
__device__ __forceinline__ void gload_lds16(const unsigned short* g, unsigned short* l) {
    __builtin_amdgcn_global_load_lds(
        (const __attribute__((address_space(1))) void*)g,
        (__attribute__((address_space(3))) void*)l, 16, 0, 0);
}

union Pack8 { unsigned short s[8]; uint4 v; };

// Transpose + cast: W[R,C] fp32 -> WT[C,R] bf16. Grid (C/32, R/32), 256 thr.
__global__ __launch_bounds__(256) void transpose_cast(
    const float* __restrict__ W, unsigned short* __restrict__ WT, int R, int C)
{
    __shared__ float t[32][33];
    const int tx = threadIdx.x & 31;
    const int ty = threadIdx.x >> 5;
    const int r0 = blockIdx.y * 32;
    const int c0 = blockIdx.x * 32;
    #pragma unroll
    for (int i = 0; i < 4; i++)
        t[ty + i * 8][tx] = W[(r0 + ty + i * 8) * C + c0 + tx];
    __syncthreads();
    #pragma unroll
    for (int i = 0; i < 4; i++)
        WT[(c0 + ty + i * 8) * R + r0 + tx] = f2bf(t[tx][ty + i * 8]);
}

// cast fp32 -> bf16, 8 elems/thread
__global__ __launch_bounds__(256) void cast_bf16(
    const float* __restrict__ src, unsigned short* __restrict__ dst, int n8)
{
    int i = blockIdx.x * 256 + threadIdx.x;
    if (i >= n8) return;
    const float4 f0 = *(const float4*)(src + i * 8);
    const float4 f1 = *(const float4*)(src + i * 8 + 4);
    Pack8 p;
    p.s[0] = f2bf(f0.x); p.s[1] = f2bf(f0.y); p.s[2] = f2bf(f0.z); p.s[3] = f2bf(f0.w);
    p.s[4] = f2bf(f1.x); p.s[5] = f2bf(f1.y); p.s[6] = f2bf(f1.z); p.s[7] = f2bf(f1.w);
    *(uint4*)(dst + i * 8) = p.v;
}

// ---- bf16 MFMA GEMM, B pre-transposed, global_load_lds staging -------------
// C[M,N] = A[M,K](bf16) @ BT[N,K](bf16)^T, fp32 accumulate.
// BK=64, XOR-swizzled LDS: dest row r's LDS chunk c holds source 16B-chunk
// c^(r&7), so fragment ds_read_b128s spread across all 8 bank groups
// (2 lanes/group = conflict-free) while staging stays global_load_lds
// compatible (no padding). Tile 128x128, 4 waves (2x2), 64x64/wave via
// mfma_f32_16x16x32_bf16. Split-K via gridDim.z (Kc multiple of 64).
// B row clamped to N-1; clamped rows store/read consistently (swizzle keyed
// on DEST row), garbage cols discarded by the epilogue col<N guard.
template <int ACT, int OBF16>
__global__ __launch_bounds__(256) void gemm_bt_lds(
    const unsigned short* __restrict__ A, const unsigned short* __restrict__ BT,
    void* __restrict__ Cout, const float* __restrict__ bias,
    int M, int N, int K, int lda, int ldb, int ldc, int Kc)
{
    __shared__ unsigned short As[128 * 64];
    __shared__ unsigned short Bs[128 * 64];

    const int tid  = threadIdx.x;
    const int lane = tid & 63;
    const int wave = tid >> 6;
    const int wm   = wave >> 1;
    const int wn   = wave & 1;
    const int row0 = blockIdx.y * 128;
    const int col0 = blockIdx.x * 128;
    const int lq   = lane >> 4;
    const int lm   = lane & 15;
    const int kbeg = blockIdx.z * Kc;

    // staging: per wave 32 rows/tile, 4 issues x 8 rows. Lane fills LDS slot
    // (row = wave*32 + is*8 + (lane>>3), chunk = lane&7); source chunk is
    // XOR-swizzled by dest row's low 3 bits ((rloc+8is)&7 == (lane>>3)&7).
    const int rloc = wave * 32 + (lane >> 3);
    const int sc   = (lane & 7) ^ ((lane >> 3) & 7);
    const unsigned short* gA = A + (size_t)(row0 + rloc) * lda + sc * 8;
    const unsigned short* gBp[4];
    #pragma unroll
    for (int is = 0; is < 4; is++) {
        int br = col0 + rloc + 8 * is;
        if (br > N - 1) br = N - 1;
        gBp[is] = BT + (size_t)br * ldb + sc * 8;
    }
    unsigned short* lA = As + wave * 2048;
    unsigned short* lB = Bs + wave * 2048;

    f32x4 acc[4][4];
    #pragma unroll
    for (int i = 0; i < 4; i++)
        #pragma unroll
        for (int j = 0; j < 4; j++)
            #pragma unroll
            for (int r = 0; r < 4; r++) acc[i][j][r] = 0.0f;

    for (int k0 = kbeg; k0 < kbeg + Kc; k0 += 64) {
        #pragma unroll
        for (int is = 0; is < 4; is++) {
            gload_lds16(gA + (size_t)(8 * is) * lda + k0, lA + is * 512);
            gload_lds16(gBp[is] + k0, lB + is * 512);
        }
        __syncthreads();

        #pragma unroll
        for (int ks = 0; ks < 2; ks++) {
            bf16x8 af[4], bfr[4];
            #pragma unroll
            for (int i = 0; i < 4; i++) {
                int row = wm * 64 + i * 16 + lm;
                af[i] = *(const bf16x8*)&As[row * 64 + (((ks * 4 + lq) ^ (row & 7)) * 8)];
            }
            #pragma unroll
            for (int j = 0; j < 4; j++) {
                int row = wn * 64 + j * 16 + lm;
                bfr[j] = *(const bf16x8*)&Bs[row * 64 + (((ks * 4 + lq) ^ (row & 7)) * 8)];
            }
            #pragma unroll
            for (int i = 0; i < 4; i++)
                #pragma unroll
                for (int j = 0; j < 4; j++)
                    acc[i][j] = __builtin_amdgcn_mfma_f32_16x16x32_bf16(
                        af[i], bfr[j], acc[i][j], 0, 0, 0);
        }
        __syncthreads();
    }

    // epilogue: C/D layout col=lane&15, row=(lane>>4)*4+reg
    #pragma unroll
    for (int i = 0; i < 4; i++) {
        #pragma unroll
        for (int r = 0; r < 4; r++) {
            int row = row0 + wm * 64 + i * 16 + lq * 4 + r;
            #pragma unroll
            for (int j = 0; j < 4; j++) {
                int col = col0 + wn * 64 + j * 16 + lm;
                if (col < N) {
                    float v = acc[i][j][r];
                    if (ACT == 1) v = softplus_f(v + bias[col]);
                    if (OBF16) {
                        unsigned short* Cz = (unsigned short*)Cout +
                            (size_t)blockIdx.z * (size_t)M * ldc;
                        Cz[(size_t)row * ldc + col] = f2bf(v);
                    } else {
                        float* Cz = (float*)Cout +
                            (size_t)blockIdx.z * (size_t)M * ldc;
                        Cz[(size_t)row * ldc + col] = v;
                    }
                }
            }
        }
    }
}

// Sum nsplit partial C buffers; also emit bf16 copy of cols<64 (dt_lo).
__global__ __launch_bounds__(256) void reduce_splitk(
    const float* __restrict__ part, float* __restrict__ C,
    unsigned short* __restrict__ dtlo16, int n, int nsplit)
{
    int i = blockIdx.x * 256 + threadIdx.x;
    if (i >= n) return;
    float s = 0.0f;
    for (int z = 0; z < nsplit; z++) s += part[(size_t)z * n + i];
    C[i] = s;
    int row = i / 96;
    int col = i - row * 96;
    if (col < DTRANK) dtlo16[row * DTRANK + col] = f2bf(s);
}

// conv + silu, register-rolling window along l. Reads bf16 xz (cols 0..2048),
// emits bf16 xc16. grid (8, 64, 2).
__global__ __launch_bounds__(256) void conv_silu_v2(
    const unsigned short* __restrict__ xz16, const float* __restrict__ conv_w,
    const float* __restrict__ conv_b, unsigned short* __restrict__ xc16)
{
    const int tid = threadIdx.x;
    const int d   = blockIdx.x * 256 + tid;
    const int l0  = blockIdx.y * 32;
    const int b   = blockIdx.z;
    const float4 w  = *(const float4*)(conv_w + d * 4);
    const float bias = conv_b[d];
    const int t0 = b * L_SZ + l0;
    const unsigned short* src = xz16 + (size_t)t0 * 4096 + d;

    float r0, r1, r2;
    if (l0 == 0) {
        r0 = r1 = r2 = 0.0f;
    } else {
        r0 = bf2f(src[-3 * 4096]);
        r1 = bf2f(src[-2 * 4096]);
        r2 = bf2f(src[-1 * 4096]);
    }
    #pragma unroll 4
    for (int l = 0; l < 32; l++) {
        float r3 = bf2f(src[(size_t)l * 4096]);
        float acc = bias + r0 * w.x + r1 * w.y + r2 * w.z + r3 * w.w;
        xc16[(size_t)(t0 + l) * DINNER + d] = f2bf(silu_f(acc));
        r0 = r1; r1 = r2; r2 = r3;
    }
}

// ---- Chunked parallel selective scan ----------------------------------------
__global__ __launch_bounds__(256) void scan_pass1(
    const unsigned short* __restrict__ xc16, const float* __restrict__ delta,
    const float* __restrict__ dbc, const float* __restrict__ A_log,
    float* __restrict__ P, float* __restrict__ E)
{
    __shared__ float Bs[CS * DSTATE];
    const int tid = threadIdx.x;
    const int db  = blockIdx.x & 7;
    const int c   = (blockIdx.x >> 3) & (NCH - 1);
    const int b   = blockIdx.x >> 8;
    const int d   = db * 256 + tid;
    const int t0  = b * L_SZ + c * CS;

    for (int idx = tid; idx < CS * DSTATE; idx += 256) {
        int step = idx >> 4, i = idx & 15;
        Bs[idx] = dbc[(t0 + step) * 96 + DTRANK + i];
    }

    float A[DSTATE], Er[DSTATE];
    #pragma unroll
    for (int s = 0; s < DSTATE; s++) {
        A[s]  = -__expf(A_log[d * DSTATE + s]);
        Er[s] = 0.0f;
    }
    float sd = 0.0f;
    __syncthreads();

    for (int l = 0; l < CS; l++) {
        const int t = t0 + l;
        float dv = delta[t * DINNER + d];
        float uv = bf2f(xc16[(size_t)t * DINNER + d]);
        float du = dv * uv;
        sd += dv;
        #pragma unroll
        for (int s = 0; s < DSTATE; s++) {
            float dA = __expf(dv * A[s]);
            Er[s] = dA * Er[s] + du * Bs[l * DSTATE + s];
        }
    }

    const long long o = ((long long)((b * NCH + c) * DINNER) + d) * DSTATE;
    #pragma unroll
    for (int s = 0; s < DSTATE; s++) {
        P[o + s] = __expf(A[s] * sd);
        E[o + s] = Er[s];
    }
}

__global__ __launch_bounds__(256) void scan_pass2(
    const float* __restrict__ P, float* __restrict__ E)
{
    const int gid  = blockIdx.x * 256 + threadIdx.x;
    const int b    = gid >> 15;
    const int rest = gid & 32767;
    float h = 0.0f;
    for (int c = 0; c < NCH; c++) {
        const long long idx = (long long)(b * NCH + c) * (DINNER * DSTATE) + rest;
        float p = P[idx];
        float e = E[idx];
        E[idx] = h;
        h = p * h + e;
    }
}

// pass3: emit y in bf16, fused silu(z) gate (z from bf16 xz cols 2048..4096).
__global__ __launch_bounds__(256) void scan_pass3(
    const unsigned short* __restrict__ xc16, const float* __restrict__ delta,
    const float* __restrict__ dbc, const float* __restrict__ A_log,
    const float* __restrict__ D_skip, const float* __restrict__ Hin,
    const unsigned short* __restrict__ xz16, unsigned short* __restrict__ y16)
{
    __shared__ float BCs[CS * 2 * DSTATE];
    const int tid = threadIdx.x;
    const int db  = blockIdx.x & 7;
    const int c   = (blockIdx.x >> 3) & (NCH - 1);
    const int b   = blockIdx.x >> 8;
    const int d   = db * 256 + tid;
    const int t0  = b * L_SZ + c * CS;

    for (int idx = tid; idx < CS * 2 * DSTATE; idx += 256) {
        int step = idx >> 5, i = idx & 31;
        BCs[idx] = dbc[(t0 + step) * 96 + DTRANK + i];
    }

    float A[DSTATE], h[DSTATE];
    const long long o = ((long long)((b * NCH + c) * DINNER) + d) * DSTATE;
    #pragma unroll
    for (int s = 0; s < DSTATE; s++) {
        A[s] = -__expf(A_log[d * DSTATE + s]);
        h[s] = Hin[o + s];
    }
    const float Dv = D_skip[d];
    __syncthreads();

    for (int l = 0; l < CS; l++) {
        const int t = t0 + l;
        float dv = delta[t * DINNER + d];
        float uv = bf2f(xc16[(size_t)t * DINNER + d]);
        float du = dv * uv;
        float yv = 0.0f;
        #pragma unroll
        for (int s = 0; s < DSTATE; s++) {
            float dA = __expf(dv * A[s]);
            h[s] = dA * h[s] + du * BCs[l * 32 + s];
            yv  += h[s] * BCs[l * 32 + DSTATE + s];
        }
        float z = bf2f(xz16[(size_t)t * 4096 + DINNER + d]);
        y16[t * DINNER + d] = f2bf((uv * Dv + yv) * silu_f(z));
    }
}

extern "C" void kernel_launch(void* const* d_in, const int* in_sizes, int n_in,
                              void* d_out, int out_size, void* d_ws, size_t ws_size,
                              hipStream_t stream) {
    const float* x       = (const float*)d_in[0];
    const float* W_in    = (const float*)d_in[1];
    const float* conv_w  = (const float*)d_in[2];
    const float* conv_b  = (const float*)d_in[3];
    const float* W_xproj = (const float*)d_in[4];
    const float* W_dt    = (const float*)d_in[5];
    const float* b_dt    = (const float*)d_in[6];
    const float* A_log   = (const float*)d_in[7];
    const float* D_skip  = (const float*)d_in[8];
    const float* W_out   = (const float*)d_in[9];
    float* out = (float*)d_out;

    // workspace layout, float units (137 MB). All extents exact; only two
    // aliases, both provably dead-before-reuse:
    //   x16 (gemm1 A, dead after gemm1)  aliases yb16 (written at pass3)
    //   Pbuf (scan)                      aliases parts (dead after reduce)
    float* ws = (float*)d_ws;
    unsigned short* xz16   = (unsigned short*)ws;              // [0 .. 8388608) f : 4096x4096 s
    unsigned short* xc16   = (unsigned short*)(ws +  8388608); // [8388608 .. 12582912) f : 4096x2048 s
    float* dbc             = ws + 12582912;                    // [12582912 .. 12976128) f
    unsigned short* dtlo16 = (unsigned short*)(ws + 12976128); // [12976128 .. 13107200) f : 4096x64 s
    float* delta           = ws + 13107200;                    // [13107200 .. 21495808) f
    float* Ebuf            = ws + 21495808;                    // [21495808 .. 23592960) f (becomes Hin)
    float* parts           = ws + 23592960;                    // [23592960 .. 26738688) f
    float* Pbuf            = parts;                            //   alias (parts dead after reduce)
    unsigned short* yb16   = (unsigned short*)(ws + 26738688); // [26738688 .. 30932992) f : 4096x2048 s
    unsigned short* x16    = yb16;                             //   alias (x16 dead after gemm1)
    unsigned short* W_inT    = (unsigned short*)(ws + 30932992); // 4194304 s
    unsigned short* W_xprojT = (unsigned short*)(ws + 33030144); //  196608 s
    unsigned short* W_dtT    = (unsigned short*)(ws + 33128448); //  131072 s
    unsigned short* W_outT   = (unsigned short*)(ws + 33193984); // 2097152 s -> ends 34242560 f

    const int MT = 4096;  // B*L tokens

    transpose_cast<<<dim3(128, 32), 256, 0, stream>>>(W_in,    W_inT,    1024, 4096);
    transpose_cast<<<dim3(  3, 64), 256, 0, stream>>>(W_xproj, W_xprojT, 2048,   96);
    transpose_cast<<<dim3( 64,  2), 256, 0, stream>>>(W_dt,    W_dtT,      64, 2048);
    transpose_cast<<<dim3( 32, 64), 256, 0, stream>>>(W_out,   W_outT,   2048, 1024);
    cast_bf16<<<dim3(2048), 256, 0, stream>>>(x, x16, 524288);

    // 1) xz = x @ W_in              (4096 x 4096, K=1024) -> bf16
    gemm_bt_lds<0, 1><<<dim3(32, 32), 256, 0, stream>>>(
        x16, W_inT, xz16, nullptr, MT, 4096, 1024, 1024, 1024, 4096, 1024);

    // 2) xc16 = silu(causal_dwconv(xin) + b)
    conv_silu_v2<<<dim3(8, 64, 2), 256, 0, stream>>>(xz16, conv_w, conv_b, xc16);

    // 3) dbc = xc @ W_xproj         (4096 x 96, K=2048) — split-K x8
    gemm_bt_lds<0, 0><<<dim3(1, 32, 8), 256, 0, stream>>>(
        xc16, W_xprojT, parts, nullptr, MT, 96, 2048, 2048, 2048, 96, 256);
    reduce_splitk<<<dim3(1536), 256, 0, stream>>>(parts, dbc, dtlo16, MT * 96, 8);

    // 4) delta = softplus(dt_lo @ W_dt + b_dt)  (4096 x 2048, K=64)
    gemm_bt_lds<1, 0><<<dim3(16, 32), 256, 0, stream>>>(
        dtlo16, W_dtT, delta, b_dt, MT, 2048, 64, 64, 64, 2048, 64);

    // 5) chunked selective scan + fused gate (bf16 y out)
    scan_pass1<<<dim3(512), 256, 0, stream>>>(xc16, delta, dbc, A_log, Pbuf, Ebuf);
    scan_pass2<<<dim3(256), 256, 0, stream>>>(Pbuf, Ebuf);
    scan_pass3<<<dim3(512), 256, 0, stream>>>(xc16, delta, dbc, A_log, D_skip,
                                              Ebuf, xz16, yb16);

    // 6) out = y @ W_out            (4096 x 1024, K=2048)
    gemm_bt_lds<0, 0><<<dim3(8, 32), 256, 0, stream>>>(
        yb16, W_outT, out, nullptr, MT, 1024, 2048, 2048, 2048, 1024, 2048);
}